// Round 8
// baseline (169.682 us; speedup 1.0000x reference)
//
#include <hip/hip_runtime.h>
#include <math.h>
#include <limits.h>

#define BB 2
#define NN 16384
#define MM 4096
#define CCH 16
#define KK 32
#define R2 0.01f
#define EPSV 1e-8f
#define GD 10
#define CPB (GD*GD*GD)
#define CAP 56
#define NCELL (BB*CPB)                  // 2000
#define WSB_OFF 8192                    // bf16 w1 B-fragments (4KB)
#define BUCKET_OFF 16384
#define FEATT_OFF (2*1024*1024)
#define WS_GRID (BUCKET_OFF + (size_t)NCELL*CAP*16)     // ~1.81 MB
#define WS_FT   (FEATT_OFF + (size_t)BB*NN*CCH*4)       // 4.19 MB
#define NDW 512                          // bitmap dwords per wave (16384 bits)

typedef __attribute__((ext_vector_type(8))) short short8;
typedef __attribute__((ext_vector_type(4))) float v4f;

__device__ __forceinline__ short f2bf(float f) {       // RNE float->bf16
    unsigned u = __float_as_uint(f);
    unsigned r = u + 0x7FFFu + ((u >> 16) & 1u);
    return (short)(r >> 16);
}

__device__ __forceinline__ int cell_of(float x, float y, float z) {
    int cx = min(GD-1, max(0, (int)(x * 10.0f)));
    int cy = min(GD-1, max(0, (int)(y * 10.0f)));
    int cz = min(GD-1, max(0, (int)(z * 10.0f)));
    return (cx*GD + cy)*GD + cz;
}

// ws: [0]=ovf, [64..8064)=cnt[2000], [8192..12288)=w1 bf16 B-frags, [16384..)=buckets, [2MB..)=featT
__global__ void k_scatter(const float* __restrict__ xyz, const float* __restrict__ feat,
                          const float* __restrict__ w1,
                          int* __restrict__ cnt, int* __restrict__ ovf,
                          float4* __restrict__ buckets, float4* __restrict__ featT,
                          short8* __restrict__ wsB, int use_ft) {
    // one-time: pack w1 into bf16 B-fragment order (wave-invariant data)
    if (blockIdx.x == 0 && threadIdx.x < 64) {
        int l15 = threadIdx.x & 15, quad = threadIdx.x >> 4;
        #pragma unroll
        for (int u = 0; u < 4; ++u) {
            const float* wr = w1 + ((u << 4) + l15)*32 + (quad << 3);
            short8 bb;
            #pragma unroll
            for (int j = 0; j < 8; ++j) bb[j] = f2bf(wr[j]);
            wsB[threadIdx.x*4 + u] = bb;
        }
    }
    int i = blockIdx.x*256 + threadIdx.x;
    if (i >= BB*NN) return;
    const float* p = xyz + (size_t)i*3;
    int b = i >> 14;
    int n = i & (NN-1);
    float x = p[0], y = p[1], z = p[2];
    int cell = b*CPB + cell_of(x, y, z);
    int slot = atomicAdd(&cnt[cell], 1);
    if (slot < CAP)
        buckets[(size_t)cell*CAP + slot] = make_float4(x, y, z, __int_as_float(n));
    else
        *ovf = 1;
    if (use_ft) {
        const float* fb = feat + (size_t)b*CCH*NN + n;
        #pragma unroll
        for (int c4 = 0; c4 < 4; ++c4) {
            float4 t = make_float4(fb[(c4*4+0)*NN], fb[(c4*4+1)*NN],
                                   fb[(c4*4+2)*NN], fb[(c4*4+3)*NN]);
            featT[(size_t)i*4 + c4] = t;
        }
    }
}

__global__ __launch_bounds__(256, 4) void grouper_fused(
    const float* __restrict__ xyz, const float* __restrict__ new_xyz,
    const float* __restrict__ feat,
    const float* __restrict__ w0, const float* __restrict__ b0,
    const float* __restrict__ w1, const float* __restrict__ b1,
    const float* __restrict__ wxyz, const float* __restrict__ bxyz,
    const int* __restrict__ cnt, const int* __restrict__ ovf,
    const float4* __restrict__ buckets, const float4* __restrict__ featT,
    const short8* __restrict__ wsB,
    int use_grid, int use_ft,
    float* __restrict__ out)
{
    const int lane = threadIdx.x & 63;
    const int wid  = threadIdx.x >> 6;
    const int q    = (blockIdx.x << 2) + wid;
    const int b    = q >> 12;
    const int m    = q & (MM - 1);

    __shared__ int s_idx[4][KK];
    __shared__ float4 s_rel[4][KK];                      // xyz = rel, w = wk
    __shared__ __align__(16) unsigned s_bm[4][NDW];      // 2KB bitmap per wave

    const float* xb = xyz + (size_t)b * NN * 3;
    const float qx = new_xyz[((size_t)b*MM + m)*3 + 0];
    const float qy = new_xyz[((size_t)b*MM + m)*3 + 1];
    const float qz = new_xyz[((size_t)b*MM + m)*3 + 2];
    const unsigned long long below = (1ull << lane) - 1ull;

    int nfound = 0, idx0 = 0;
    bool need_full = (use_grid == 0) || (use_grid && ovf[0] != 0);

    if (!need_full) {
        // clear this wave's bitmap (in-order DS pipe: completes before atomics below)
        uint4 z4 = make_uint4(0u, 0u, 0u, 0u);
        *(uint4*)&s_bm[wid][lane*8]     = z4;
        *(uint4*)&s_bm[wid][lane*8 + 4] = z4;

        int x0 = max(0, (int)floorf((qx - 0.1f)*10.0f - 1e-3f));
        int x1 = min(GD-1, (int)floorf((qx + 0.1f)*10.0f + 1e-3f));
        int y0 = max(0, (int)floorf((qy - 0.1f)*10.0f - 1e-3f));
        int y1 = min(GD-1, (int)floorf((qy + 0.1f)*10.0f + 1e-3f));
        int z0 = max(0, (int)floorf((qz - 0.1f)*10.0f - 1e-3f));
        int z1 = min(GD-1, (int)floorf((qz + 0.1f)*10.0f + 1e-3f));

        // ---- lane -> cell via arithmetic decomposition; one parallel cnt load ----
        const int nzc = z1 - z0 + 1, nyc = y1 - y0 + 1, nxc = x1 - x0 + 1;
        const int nyz = nyc * nzc;
        const int ncells = nxc * nyz;
        int myCnt = 0, myBase = 0;
        if (lane < ncells) {
            const float rnyz = 1.0f / (float)nyz;
            const float rnz  = 1.0f / (float)nzc;
            int cx = (int)((float)lane * rnyz + 1e-4f);
            int rem = lane - cx * nyz;
            int cy = (int)((float)rem * rnz + 1e-4f);
            int cz = rem - cy * nzc;
            int cell = b*CPB + ((x0+cx)*GD + (y0+cy))*GD + (z0+cz);
            myCnt = min(cnt[cell], CAP);
            myBase = cell * CAP;
        }

        __builtin_amdgcn_wave_barrier();

        // ---- 4 cells per iteration: independent clamped loads, gated tests ----
        for (int c = 0; c < ncells; c += 4) {
            int cc[4], cb[4];
            #pragma unroll
            for (int u = 0; u < 4; ++u) {
                int ci = c + u;
                cc[u] = (ci < ncells) ? __builtin_amdgcn_readlane(myCnt, ci) : 0;
                cb[u] = (ci < ncells) ? __builtin_amdgcn_readlane(myBase, ci) : 0;
            }
            float4 p[4];
            #pragma unroll
            for (int u = 0; u < 4; ++u)
                p[u] = buckets[cb[u] + ((lane < cc[u]) ? lane : 0)];
            #pragma unroll
            for (int u = 0; u < 4; ++u) {
                if (lane < cc[u]) {
                    float dx = p[u].x - qx, dy = p[u].y - qy, dz = p[u].z - qz;
                    if (dx*dx + dy*dy + dz*dz < R2) {
                        int id = __float_as_int(p[u].w);
                        atomicOr(&s_bm[wid][id >> 5], 1u << (id & 31));
                    }
                }
            }
        }

        __builtin_amdgcn_wave_barrier();

        // ---- bitmap -> first K indices (ascending). lane owns dwords [8l, 8l+8) ----
        uint4 d0 = *(uint4*)&s_bm[wid][lane*8];
        uint4 d1 = *(uint4*)&s_bm[wid][lane*8 + 4];
        unsigned dw[8] = {d0.x, d0.y, d0.z, d0.w, d1.x, d1.y, d1.z, d1.w};
        int pc = 0;
        #pragma unroll
        for (int j = 0; j < 8; ++j) pc += __popc(dw[j]);
        int pre = pc;
        #pragma unroll
        for (int d = 1; d < 64; d <<= 1) {
            int t = __shfl_up(pre, d);
            if (lane >= d) pre += t;
        }
        int total = __shfl(pre, 63);
        int rank = pre - pc;                  // exclusive prefix
        nfound = min(total, KK);

        if (rank < KK) {
            #pragma unroll
            for (int j = 0; j < 8; ++j) {
                unsigned bits = dw[j];
                while (bits && rank < KK) {
                    int bpos = __builtin_ctz(bits);
                    s_idx[wid][rank] = ((lane*8 + j) << 5) + bpos;
                    bits &= bits - 1;
                    ++rank;
                }
            }
        }

        __builtin_amdgcn_wave_barrier();
        idx0 = (nfound > 0) ? s_idx[wid][0] : 0;
        __builtin_amdgcn_wave_barrier();
        if (lane >= nfound && lane < KK) s_idx[wid][lane] = idx0;
        __builtin_amdgcn_wave_barrier();
    }

    if (need_full) {
        int cntf = 0;
        for (int basep = 0; basep < NN; basep += 256) {
            float d2a[4];
            #pragma unroll
            for (int j = 0; j < 4; ++j) {
                int i = basep + (j << 6) + lane;
                float px = xb[i*3+0], py = xb[i*3+1], pz = xb[i*3+2];
                float dx = px - qx, dy = py - qy, dz = pz - qz;
                d2a[j] = dx*dx + dy*dy + dz*dz;
            }
            #pragma unroll
            for (int j = 0; j < 4; ++j) {
                bool hit = d2a[j] < R2;
                unsigned long long msk = __ballot(hit);
                if (hit) {
                    int pos = cntf + __popcll(msk & below);
                    if (pos < KK) s_idx[wid][pos] = basep + (j << 6) + lane;
                }
                cntf += __popcll(msk);
            }
            if (cntf >= KK) break;
        }
        nfound = cntf < KK ? cntf : KK;
        __builtin_amdgcn_wave_barrier();
        if (lane < KK) {
            int v = 0;
            if (nfound > 0) v = (lane < nfound) ? s_idx[wid][lane] : s_idx[wid][0];
            s_idx[wid][lane] = v;
        }
        __builtin_amdgcn_wave_barrier();
        idx0 = s_idx[wid][0];
    }

    // ---------- rel coords + normalized weights (k = lane&31) ----------
    {
        const int k = lane & 31;
        const int h = lane >> 5;
        const int ik = s_idx[wid][k];
        float px = xb[ik*3+0], py = xb[ik*3+1], pz = xb[ik*3+2];
        float rx = px - qx, ry = py - qy, rz = pz - qz;
        float dist = sqrtf(rx*rx + ry*ry + rz*rz);
        float recip = 1.0f / (dist + EPSV);
        float mult = (float)(1 + KK - nfound);
        float w = recip / ((ik == idx0) ? mult : 1.0f);
        float S = w;
        #pragma unroll
        for (int d = 1; d < 32; d <<= 1) S += __shfl_xor(S, d);
        float wk = (nfound > 0) ? (w / S) : 0.0f;
        if (h == 0) s_rel[wid][k] = make_float4(rx, ry, rz, wk);
    }
    __builtin_amdgcn_wave_barrier();

    // ---------- MFMA MLP: lane = (l15, quad) ----------
    const int l15 = lane & 15;
    const int quad = lane >> 4;
    const int ik0 = s_idx[wid][l15];
    const int ik1 = s_idx[wid][16 + l15];

    float g0[CCH], g1[CCH];
    if (use_ft) {
        const float4* f0 = featT + ((size_t)(b*NN + ik0)) * 4;
        const float4* f1 = featT + ((size_t)(b*NN + ik1)) * 4;
        #pragma unroll
        for (int c4 = 0; c4 < 4; ++c4) {
            float4 a = f0[c4], c = f1[c4];
            g0[c4*4+0] = a.x; g0[c4*4+1] = a.y; g0[c4*4+2] = a.z; g0[c4*4+3] = a.w;
            g1[c4*4+0] = c.x; g1[c4*4+1] = c.y; g1[c4*4+2] = c.z; g1[c4*4+3] = c.w;
        }
    } else {
        const float* fb = feat + (size_t)b * CCH * NN;
        #pragma unroll
        for (int c = 0; c < CCH; ++c) { g0[c] = fb[c*NN + ik0]; g1[c] = fb[c*NN + ik1]; }
    }

    // h0 channels [8q, 8q+8) for both neighbors -> A fragments (no transpose)
    short8 A0, A1;
    #pragma unroll
    for (int j = 0; j < 8; ++j) {
        const int o = (quad << 3) + j;
        const float* wr = w0 + o*CCH;
        float a0 = 0.f, a1 = 0.f;
        #pragma unroll
        for (int c = 0; c < CCH; ++c) { a0 += wr[c]*g0[c]; a1 += wr[c]*g1[c]; }
        float bo = b0[o];
        A0[j] = f2bf(fmaxf(a0 + bo, 0.0f));
        A1[j] = f2bf(fmaxf(a1 + bo, 0.0f));
    }

    // B fragments: precomputed bf16 w1 (wave-invariant), or inline fallback
    short8 Bf[4];
    if (use_grid) {
        #pragma unroll
        for (int u = 0; u < 4; ++u) Bf[u] = wsB[lane*4 + u];
    } else {
        #pragma unroll
        for (int u = 0; u < 4; ++u) {
            const float* wr = w1 + ((u << 4) + l15)*32 + (quad << 3);
            short8 bb;
            #pragma unroll
            for (int j = 0; j < 8; ++j) bb[j] = f2bf(wr[j]);
            Bf[u] = bb;
        }
    }

    v4f zero4 = {0.f, 0.f, 0.f, 0.f};
    v4f D[2][4];
    #pragma unroll
    for (int u = 0; u < 4; ++u) {
        D[0][u] = __builtin_amdgcn_mfma_f32_16x16x32_bf16(A0, Bf[u], zero4, 0, 0, 0);
        D[1][u] = __builtin_amdgcn_mfma_f32_16x16x32_bf16(A1, Bf[u], zero4, 0, 0, 0);
    }

    // wk for this lane's 8 rows: k = 16t + 4*quad + r
    float wkv[2][4];
    #pragma unroll
    for (int t = 0; t < 2; ++t)
        #pragma unroll
        for (int r = 0; r < 4; ++r)
            wkv[t][r] = s_rel[wid][16*t + (quad << 2) + r].w;

    float* out2 = out + (size_t)BB*MM*3 + (size_t)b*96*MM;

    float Su[4];
    #pragma unroll
    for (int u = 0; u < 4; ++u) {
        const float b1O = b1[(u << 4) + l15];
        float s = 0.f;
        #pragma unroll
        for (int t = 0; t < 2; ++t)
            #pragma unroll
            for (int r = 0; r < 4; ++r)
                s += wkv[t][r] * fmaxf(D[t][u][r] + b1O, 0.0f);
        s += __shfl_xor(s, 16);
        s += __shfl_xor(s, 32);
        Su[u] = s;
    }
    float sout = (quad == 0) ? Su[0] : (quad == 1) ? Su[1] : (quad == 2) ? Su[2] : Su[3];
    out2[(32 + lane)*MM + m] = sout;   // O = 16*quad + l15 = lane

    // ---------- xyz branch: lane = channel c, halves split k, max-pool ----------
    {
        const int c = lane & 31;
        const int h = lane >> 5;
        const float wx0 = wxyz[c*3+0], wx1 = wxyz[c*3+1], wx2 = wxyz[c*3+2];
        const float bc = bxyz[c];
        float v = 0.0f;
        #pragma unroll
        for (int kk = 0; kk < 16; ++kk) {
            float4 hr = s_rel[wid][(h << 4) + kk];
            float t = bc + wx0*hr.x + wx1*hr.y + wx2*hr.z;
            v = fmaxf(v, fmaxf(t, 0.0f));
        }
        v = fmaxf(v, __shfl_xor(v, 32));
        if (h == 0) out2[c*MM + m] = v;
    }

    if (lane == 0) {
        float* o0 = out + ((size_t)b*MM + m)*3;
        o0[0] = qx; o0[1] = qy; o0[2] = qz;
    }
}

extern "C" void kernel_launch(void* const* d_in, const int* in_sizes, int n_in,
                              void* d_out, int out_size, void* d_ws, size_t ws_size,
                              hipStream_t stream) {
    const float* xyz     = (const float*)d_in[0];
    const float* new_xyz = (const float*)d_in[1];
    const float* feat    = (const float*)d_in[2];
    const float* w0      = (const float*)d_in[3];
    const float* b0      = (const float*)d_in[4];
    const float* w1      = (const float*)d_in[5];
    const float* b1      = (const float*)d_in[6];
    const float* wxyz    = (const float*)d_in[7];
    const float* bxyz    = (const float*)d_in[8];
    float* out = (float*)d_out;

    int* ovf = (int*)d_ws;
    int* cnt = (int*)((char*)d_ws + 64);
    short8* wsB = (short8*)((char*)d_ws + WSB_OFF);
    float4* buckets = (float4*)((char*)d_ws + BUCKET_OFF);
    float4* featT   = (float4*)((char*)d_ws + FEATT_OFF);
    const int use_grid = (d_ws != nullptr && ws_size >= WS_GRID) ? 1 : 0;
    const int use_ft   = (d_ws != nullptr && ws_size >= WS_FT) ? 1 : 0;

    if (use_grid) {
        hipMemsetAsync(d_ws, 0, BUCKET_OFF, stream);
        hipLaunchKernelGGL(k_scatter, dim3((BB*NN+255)/256), dim3(256), 0, stream,
                           xyz, feat, w1, cnt, ovf, buckets, featT, wsB, use_ft);
    }
    hipLaunchKernelGGL(grouper_fused, dim3((BB*MM)/4), dim3(256), 0, stream,
                       xyz, new_xyz, feat, w0, b0, w1, b1, wxyz, bxyz,
                       cnt, ovf, buckets, featT, wsB, use_grid, use_ft, out);
}

// Round 9
// 120.557 us; speedup vs baseline: 1.4075x; 1.4075x over previous
//
#include <hip/hip_runtime.h>
#include <math.h>
#include <limits.h>

#define BB 2
#define NN 16384
#define MM 4096
#define CCH 16
#define KK 32
#define R2 0.01f
#define EPSV 1e-8f
#define GD 10
#define CPB (GD*GD*GD)
#define CAP 56
#define NCELL (BB*CPB)                  // 2000
#define BUCKET_OFF 16384
#define FEATT_OFF (2*1024*1024)
#define WS_GRID (BUCKET_OFF + (size_t)NCELL*CAP*16)     // ~1.81 MB
#define WS_FT   (FEATT_OFF + (size_t)BB*NN*CCH*4)       // 4.19 MB
#define NDW 512                          // bitmap dwords per wave (16384 bits)

typedef __attribute__((ext_vector_type(8))) short short8;
typedef __attribute__((ext_vector_type(4))) float v4f;

__device__ __forceinline__ short f2bf(float f) {       // RNE float->bf16
    unsigned u = __float_as_uint(f);
    unsigned r = u + 0x7FFFu + ((u >> 16) & 1u);
    return (short)(r >> 16);
}

__device__ __forceinline__ int cell_of(float x, float y, float z) {
    int cx = min(GD-1, max(0, (int)(x * 10.0f)));
    int cy = min(GD-1, max(0, (int)(y * 10.0f)));
    int cz = min(GD-1, max(0, (int)(z * 10.0f)));
    return (cx*GD + cy)*GD + cz;
}

// ws: [0]=ovf, [64..8064)=cnt[2000], [16384..)=buckets, [2MB..)=featT [B*N][16]
__global__ void k_scatter(const float* __restrict__ xyz, const float* __restrict__ feat,
                          int* __restrict__ cnt, int* __restrict__ ovf,
                          float4* __restrict__ buckets, float4* __restrict__ featT,
                          int use_ft) {
    int i = blockIdx.x*256 + threadIdx.x;
    if (i >= BB*NN) return;
    const float* p = xyz + (size_t)i*3;
    int b = i >> 14;
    int n = i & (NN-1);
    float x = p[0], y = p[1], z = p[2];
    int cell = b*CPB + cell_of(x, y, z);
    int slot = atomicAdd(&cnt[cell], 1);
    if (slot < CAP)
        buckets[(size_t)cell*CAP + slot] = make_float4(x, y, z, __int_as_float(n));
    else
        *ovf = 1;
    if (use_ft) {
        const float* fb = feat + (size_t)b*CCH*NN + n;
        #pragma unroll
        for (int c4 = 0; c4 < 4; ++c4) {
            float4 t = make_float4(fb[(c4*4+0)*NN], fb[(c4*4+1)*NN],
                                   fb[(c4*4+2)*NN], fb[(c4*4+3)*NN]);
            featT[(size_t)i*4 + c4] = t;
        }
    }
}

__global__ __launch_bounds__(256, 4) void grouper_fused(
    const float* __restrict__ xyz, const float* __restrict__ new_xyz,
    const float* __restrict__ feat,
    const float* __restrict__ w0, const float* __restrict__ b0,
    const float* __restrict__ w1, const float* __restrict__ b1,
    const float* __restrict__ wxyz, const float* __restrict__ bxyz,
    const int* __restrict__ cnt, const int* __restrict__ ovf,
    const float4* __restrict__ buckets, const float4* __restrict__ featT,
    int use_grid, int use_ft,
    float* __restrict__ out)
{
    const int lane = threadIdx.x & 63;
    const int wid  = threadIdx.x >> 6;
    const int q    = (blockIdx.x << 2) + wid;
    const int b    = q >> 12;
    const int m    = q & (MM - 1);

    __shared__ int s_idx[4][KK];
    __shared__ float4 s_rel[4][KK];                      // xyz = rel, w = wk
    __shared__ __align__(16) unsigned s_bm[4][NDW];      // 2KB bitmap per wave

    const float* xb = xyz + (size_t)b * NN * 3;
    const float qx = new_xyz[((size_t)b*MM + m)*3 + 0];
    const float qy = new_xyz[((size_t)b*MM + m)*3 + 1];
    const float qz = new_xyz[((size_t)b*MM + m)*3 + 2];
    const unsigned long long below = (1ull << lane) - 1ull;

    int nfound = 0, idx0 = 0;
    bool need_full = (use_grid == 0) || (use_grid && ovf[0] != 0);

    if (!need_full) {
        // clear this wave's bitmap (in-order DS pipe: completes before atomics below)
        uint4 z4 = make_uint4(0u, 0u, 0u, 0u);
        *(uint4*)&s_bm[wid][lane*8]     = z4;
        *(uint4*)&s_bm[wid][lane*8 + 4] = z4;

        int x0 = max(0, (int)floorf((qx - 0.1f)*10.0f - 1e-3f));
        int x1 = min(GD-1, (int)floorf((qx + 0.1f)*10.0f + 1e-3f));
        int y0 = max(0, (int)floorf((qy - 0.1f)*10.0f - 1e-3f));
        int y1 = min(GD-1, (int)floorf((qy + 0.1f)*10.0f + 1e-3f));
        int z0 = max(0, (int)floorf((qz - 0.1f)*10.0f - 1e-3f));
        int z1 = min(GD-1, (int)floorf((qz + 0.1f)*10.0f + 1e-3f));

        // ---- assign cells to lanes (wave-uniform loop), one parallel cnt load ----
        int myCell = -1, ncells = 0;
        int myCx = 0, myCy = 0, myCz = 0;
        for (int cx = x0; cx <= x1; ++cx)
        for (int cy = y0; cy <= y1; ++cy)
        for (int cz = z0; cz <= z1; ++cz) {
            if (lane == ncells) {
                myCell = b*CPB + (cx*GD + cy)*GD + cz;
                myCx = cx; myCy = cy; myCz = cz;
            }
            ++ncells;
        }
        int myCnt = 0, myBase = 0;
        if (myCell >= 0) {
            // prune cells the query ball cannot reach (AABB min-dist test)
            float xlo = myCx*0.1f, ylo = myCy*0.1f, zlo = myCz*0.1f;
            float ddx = fmaxf(fmaxf(xlo - qx, qx - (xlo + 0.1f)), 0.0f);
            float ddy = fmaxf(fmaxf(ylo - qy, qy - (ylo + 0.1f)), 0.0f);
            float ddz = fmaxf(fmaxf(zlo - qz, qz - (zlo + 0.1f)), 0.0f);
            if (ddx*ddx + ddy*ddy + ddz*ddz < R2) {
                myCnt = min(cnt[myCell], CAP);
                myBase = myCell*CAP;
            }
        }

        __builtin_amdgcn_wave_barrier();

        // ---- per-cell point tests, depth-2 software pipeline (gated loads) ----
        int cc0 = __builtin_amdgcn_readlane(myCnt, 0);
        int cb0 = __builtin_amdgcn_readlane(myBase, 0);
        float4 p0 = make_float4(0.f, 0.f, 0.f, 0.f);
        if (lane < cc0) p0 = buckets[cb0 + lane];
        for (int c = 0; c < ncells; ++c) {
            int cc1 = 0, cb1 = 0;
            if (c + 1 < ncells) {
                cc1 = __builtin_amdgcn_readlane(myCnt, c + 1);
                cb1 = __builtin_amdgcn_readlane(myBase, c + 1);
            }
            float4 pn = make_float4(0.f, 0.f, 0.f, 0.f);
            if (lane < cc1) pn = buckets[cb1 + lane];      // prefetch next cell
            if (lane < cc0) {
                float dx = p0.x - qx, dy = p0.y - qy, dz = p0.z - qz;
                float d2 = dx*dx + dy*dy + dz*dz;
                if (d2 < R2) {
                    int id = __float_as_int(p0.w);
                    atomicOr(&s_bm[wid][id >> 5], 1u << (id & 31));
                }
            }
            cc0 = cc1; cb0 = cb1; p0 = pn;
        }

        __builtin_amdgcn_wave_barrier();

        // ---- bitmap -> first K indices (ascending). lane owns dwords [8l, 8l+8) ----
        uint4 d0 = *(uint4*)&s_bm[wid][lane*8];
        uint4 d1 = *(uint4*)&s_bm[wid][lane*8 + 4];
        unsigned dw[8] = {d0.x, d0.y, d0.z, d0.w, d1.x, d1.y, d1.z, d1.w};
        int pc = 0;
        #pragma unroll
        for (int j = 0; j < 8; ++j) pc += __popc(dw[j]);
        int pre = pc;
        #pragma unroll
        for (int d = 1; d < 64; d <<= 1) {
            int t = __shfl_up(pre, d);
            if (lane >= d) pre += t;
        }
        int total = __shfl(pre, 63);
        int rank = pre - pc;                  // exclusive prefix
        nfound = min(total, KK);

        if (rank < KK) {
            #pragma unroll
            for (int j = 0; j < 8; ++j) {
                unsigned bits = dw[j];
                while (bits && rank < KK) {
                    int bpos = __builtin_ctz(bits);
                    s_idx[wid][rank] = ((lane*8 + j) << 5) + bpos;
                    bits &= bits - 1;
                    ++rank;
                }
            }
        }

        __builtin_amdgcn_wave_barrier();
        idx0 = (nfound > 0) ? s_idx[wid][0] : 0;
        __builtin_amdgcn_wave_barrier();
        if (lane >= nfound && lane < KK) s_idx[wid][lane] = idx0;
        __builtin_amdgcn_wave_barrier();
    }

    if (need_full) {
        int cntf = 0;
        for (int basep = 0; basep < NN; basep += 256) {
            float d2a[4];
            #pragma unroll
            for (int j = 0; j < 4; ++j) {
                int i = basep + (j << 6) + lane;
                float px = xb[i*3+0], py = xb[i*3+1], pz = xb[i*3+2];
                float dx = px - qx, dy = py - qy, dz = pz - qz;
                d2a[j] = dx*dx + dy*dy + dz*dz;
            }
            #pragma unroll
            for (int j = 0; j < 4; ++j) {
                bool hit = d2a[j] < R2;
                unsigned long long msk = __ballot(hit);
                if (hit) {
                    int pos = cntf + __popcll(msk & below);
                    if (pos < KK) s_idx[wid][pos] = basep + (j << 6) + lane;
                }
                cntf += __popcll(msk);
            }
            if (cntf >= KK) break;
        }
        nfound = cntf < KK ? cntf : KK;
        __builtin_amdgcn_wave_barrier();
        if (lane < KK) {
            int v = 0;
            if (nfound > 0) v = (lane < nfound) ? s_idx[wid][lane] : s_idx[wid][0];
            s_idx[wid][lane] = v;
        }
        __builtin_amdgcn_wave_barrier();
        idx0 = s_idx[wid][0];
    }

    // ---------- rel coords + normalized weights (k = lane&31) ----------
    {
        const int k = lane & 31;
        const int h = lane >> 5;
        const int ik = s_idx[wid][k];
        float px = xb[ik*3+0], py = xb[ik*3+1], pz = xb[ik*3+2];
        float rx = px - qx, ry = py - qy, rz = pz - qz;
        float dist = sqrtf(rx*rx + ry*ry + rz*rz);
        float recip = 1.0f / (dist + EPSV);
        float mult = (float)(1 + KK - nfound);
        float w = recip / ((ik == idx0) ? mult : 1.0f);
        float S = w;
        #pragma unroll
        for (int d = 1; d < 32; d <<= 1) S += __shfl_xor(S, d);
        float wk = (nfound > 0) ? (w / S) : 0.0f;
        if (h == 0) s_rel[wid][k] = make_float4(rx, ry, rz, wk);
    }
    __builtin_amdgcn_wave_barrier();

    // ---------- MFMA MLP: lane = (l15, quad) ----------
    const int l15 = lane & 15;
    const int quad = lane >> 4;
    const int ik0 = s_idx[wid][l15];
    const int ik1 = s_idx[wid][16 + l15];

    float g0[CCH], g1[CCH];
    if (use_ft) {
        const float4* f0 = featT + ((size_t)(b*NN + ik0)) * 4;
        const float4* f1 = featT + ((size_t)(b*NN + ik1)) * 4;
        #pragma unroll
        for (int c4 = 0; c4 < 4; ++c4) {
            float4 a = f0[c4], c = f1[c4];
            g0[c4*4+0] = a.x; g0[c4*4+1] = a.y; g0[c4*4+2] = a.z; g0[c4*4+3] = a.w;
            g1[c4*4+0] = c.x; g1[c4*4+1] = c.y; g1[c4*4+2] = c.z; g1[c4*4+3] = c.w;
        }
    } else {
        const float* fb = feat + (size_t)b * CCH * NN;
        #pragma unroll
        for (int c = 0; c < CCH; ++c) { g0[c] = fb[c*NN + ik0]; g1[c] = fb[c*NN + ik1]; }
    }

    // h0 channels [8q, 8q+8) for both neighbors -> A fragments (no transpose)
    short8 A0, A1;
    #pragma unroll
    for (int j = 0; j < 8; ++j) {
        const int o = (quad << 3) + j;
        const float* wr = w0 + o*CCH;
        float a0 = 0.f, a1 = 0.f;
        #pragma unroll
        for (int c = 0; c < CCH; ++c) { a0 += wr[c]*g0[c]; a1 += wr[c]*g1[c]; }
        float bo = b0[o];
        A0[j] = f2bf(fmaxf(a0 + bo, 0.0f));
        A1[j] = f2bf(fmaxf(a1 + bo, 0.0f));
    }

    // B fragments: w1[16u+l15][8q..8q+8)
    short8 Bf[4];
    #pragma unroll
    for (int u = 0; u < 4; ++u) {
        const float* wr = w1 + ((u << 4) + l15)*32 + (quad << 3);
        float4 p = *(const float4*)(wr);
        float4 r = *(const float4*)(wr + 4);
        short8 bb;
        bb[0]=f2bf(p.x); bb[1]=f2bf(p.y); bb[2]=f2bf(p.z); bb[3]=f2bf(p.w);
        bb[4]=f2bf(r.x); bb[5]=f2bf(r.y); bb[6]=f2bf(r.z); bb[7]=f2bf(r.w);
        Bf[u] = bb;
    }

    v4f zero4 = {0.f, 0.f, 0.f, 0.f};
    v4f D[2][4];
    #pragma unroll
    for (int u = 0; u < 4; ++u) {
        D[0][u] = __builtin_amdgcn_mfma_f32_16x16x32_bf16(A0, Bf[u], zero4, 0, 0, 0);
        D[1][u] = __builtin_amdgcn_mfma_f32_16x16x32_bf16(A1, Bf[u], zero4, 0, 0, 0);
    }

    // wk for this lane's 8 rows: k = 16t + 4*quad + r
    float wkv[2][4];
    #pragma unroll
    for (int t = 0; t < 2; ++t)
        #pragma unroll
        for (int r = 0; r < 4; ++r)
            wkv[t][r] = s_rel[wid][16*t + (quad << 2) + r].w;

    float* out2 = out + (size_t)BB*MM*3 + (size_t)b*96*MM;

    float Su[4];
    #pragma unroll
    for (int u = 0; u < 4; ++u) {
        const float b1O = b1[(u << 4) + l15];
        float s = 0.f;
        #pragma unroll
        for (int t = 0; t < 2; ++t)
            #pragma unroll
            for (int r = 0; r < 4; ++r)
                s += wkv[t][r] * fmaxf(D[t][u][r] + b1O, 0.0f);
        s += __shfl_xor(s, 16);
        s += __shfl_xor(s, 32);
        Su[u] = s;
    }
    float sout = (quad == 0) ? Su[0] : (quad == 1) ? Su[1] : (quad == 2) ? Su[2] : Su[3];
    out2[(32 + lane)*MM + m] = sout;   // O = 16*quad + l15 = lane

    // ---------- xyz branch: lane = channel c, halves split k, max-pool ----------
    {
        const int c = lane & 31;
        const int h = lane >> 5;
        const float wx0 = wxyz[c*3+0], wx1 = wxyz[c*3+1], wx2 = wxyz[c*3+2];
        const float bc = bxyz[c];
        float v = 0.0f;
        #pragma unroll
        for (int kk = 0; kk < 16; ++kk) {
            float4 hr = s_rel[wid][(h << 4) + kk];
            float t = bc + wx0*hr.x + wx1*hr.y + wx2*hr.z;
            v = fmaxf(v, fmaxf(t, 0.0f));
        }
        v = fmaxf(v, __shfl_xor(v, 32));
        if (h == 0) out2[c*MM + m] = v;
    }

    if (lane == 0) {
        float* o0 = out + ((size_t)b*MM + m)*3;
        o0[0] = qx; o0[1] = qy; o0[2] = qz;
    }
}

extern "C" void kernel_launch(void* const* d_in, const int* in_sizes, int n_in,
                              void* d_out, int out_size, void* d_ws, size_t ws_size,
                              hipStream_t stream) {
    const float* xyz     = (const float*)d_in[0];
    const float* new_xyz = (const float*)d_in[1];
    const float* feat    = (const float*)d_in[2];
    const float* w0      = (const float*)d_in[3];
    const float* b0      = (const float*)d_in[4];
    const float* w1      = (const float*)d_in[5];
    const float* b1      = (const float*)d_in[6];
    const float* wxyz    = (const float*)d_in[7];
    const float* bxyz    = (const float*)d_in[8];
    float* out = (float*)d_out;

    int* ovf = (int*)d_ws;
    int* cnt = (int*)((char*)d_ws + 64);
    float4* buckets = (float4*)((char*)d_ws + BUCKET_OFF);
    float4* featT   = (float4*)((char*)d_ws + FEATT_OFF);
    const int use_grid = (d_ws != nullptr && ws_size >= WS_GRID) ? 1 : 0;
    const int use_ft   = (d_ws != nullptr && ws_size >= WS_FT) ? 1 : 0;

    if (use_grid) {
        hipMemsetAsync(d_ws, 0, BUCKET_OFF, stream);
        hipLaunchKernelGGL(k_scatter, dim3((BB*NN+255)/256), dim3(256), 0, stream,
                           xyz, feat, cnt, ovf, buckets, featT, use_ft);
    }
    hipLaunchKernelGGL(grouper_fused, dim3((BB*MM)/4), dim3(256), 0, stream,
                       xyz, new_xyz, feat, w0, b0, w1, b1, wxyz, bxyz,
                       cnt, ovf, buckets, featT, use_grid, use_ft, out);
}

// Round 10
// 115.885 us; speedup vs baseline: 1.4642x; 1.0403x over previous
//
#include <hip/hip_runtime.h>
#include <math.h>
#include <limits.h>

#define BB 2
#define NN 16384
#define MM 4096
#define CCH 16
#define KK 32
#define R2 0.01f
#define EPSV 1e-8f
#define GD 10
#define CPB (GD*GD*GD)
#define CAP 56
#define NCELL (BB*CPB)                  // 2000
#define WSA_OFF 8192                    // w0 A-frags: 128 short8 = 2KB
#define WSB_OFF 10240                   // w1 B-frags: 256 short8 = 4KB
#define BUCKET_OFF 16384
#define WS_GRID (BUCKET_OFF + (size_t)NCELL*CAP*16)     // ~1.81 MB
#define NDW 512                          // bitmap dwords per wave (16384 bits)

typedef __attribute__((ext_vector_type(8))) short short8;
typedef __attribute__((ext_vector_type(4))) float v4f;

__device__ __forceinline__ short f2bf(float f) {       // RNE float->bf16
    unsigned u = __float_as_uint(f);
    unsigned r = u + 0x7FFFu + ((u >> 16) & 1u);
    return (short)(r >> 16);
}
__device__ __forceinline__ unsigned pk2(float a, float b) {  // pack 2 bf16
    return (unsigned)(unsigned short)f2bf(a) | ((unsigned)(unsigned short)f2bf(b) << 16);
}

__device__ __forceinline__ int cell_of(float x, float y, float z) {
    int cx = min(GD-1, max(0, (int)(x * 10.0f)));
    int cy = min(GD-1, max(0, (int)(y * 10.0f)));
    int cz = min(GD-1, max(0, (int)(z * 10.0f)));
    return (cx*GD + cy)*GD + cz;
}

// ws: [0]=ovf, [64..8064)=cnt[2000], [8192)=wsA, [10240)=wsB, [16384..)=buckets
__global__ void k_scatter(const float* __restrict__ xyz,
                          const float* __restrict__ w0, const float* __restrict__ w1,
                          int* __restrict__ cnt, int* __restrict__ ovf,
                          float4* __restrict__ buckets,
                          short8* __restrict__ wsA, short8* __restrict__ wsB) {
    if (blockIdx.x == 0) {
        int t = threadIdx.x;
        if (t < 128) {   // w0 A-fragments (rows [0,16) and [16,32)), zero-padded K
            int fi = t >> 6, l = t & 63, l15 = l & 15, qd = (l >> 4) & 3;
            short8 a = {0,0,0,0,0,0,0,0};
            if (qd < 2)
                #pragma unroll
                for (int j = 0; j < 8; ++j)
                    a[j] = f2bf(w0[(fi*16 + l15)*CCH + qd*8 + j]);
            wsA[fi*64 + l] = a;
        }
        if (t < 64) {    // w1 B-fragments
            int l15 = t & 15, qd = t >> 4;
            #pragma unroll
            for (int u = 0; u < 4; ++u) {
                const float* wr = w1 + ((u << 4) + l15)*32 + (qd << 3);
                short8 bb;
                #pragma unroll
                for (int j = 0; j < 8; ++j) bb[j] = f2bf(wr[j]);
                wsB[t*4 + u] = bb;
            }
        }
    }
    int i = blockIdx.x*256 + threadIdx.x;
    if (i >= BB*NN) return;
    const float* p = xyz + (size_t)i*3;
    int b = i >> 14;
    int n = i & (NN-1);
    float x = p[0], y = p[1], z = p[2];
    int cell = b*CPB + cell_of(x, y, z);
    int slot = atomicAdd(&cnt[cell], 1);
    if (slot < CAP)
        buckets[(size_t)cell*CAP + slot] = make_float4(x, y, z, __int_as_float(n));
    else
        *ovf = 1;
}

__global__ __launch_bounds__(256, 4) void grouper_fused(
    const float* __restrict__ xyz, const float* __restrict__ new_xyz,
    const float* __restrict__ feat,
    const float* __restrict__ w0, const float* __restrict__ b0,
    const float* __restrict__ w1, const float* __restrict__ b1,
    const float* __restrict__ wxyz, const float* __restrict__ bxyz,
    const int* __restrict__ cnt, const int* __restrict__ ovf,
    const float4* __restrict__ buckets,
    const short8* __restrict__ wsA, const short8* __restrict__ wsB,
    int use_grid,
    float* __restrict__ out)
{
    const int lane = threadIdx.x & 63;
    const int wid  = threadIdx.x >> 6;
    const int q    = (blockIdx.x << 2) + wid;
    const int b    = q >> 12;
    const int m    = q & (MM - 1);

    __shared__ int s_idx[4][KK];
    __shared__ float4 s_rel[4][KK];                      // xyz = rel, w = wk
    __shared__ __align__(16) unsigned s_bm[4][NDW];      // 2KB bitmap per wave
    __shared__ __align__(16) short s_h0t[4][32*32];      // h0 transpose: row k, col o

    const float* xb = xyz + (size_t)b * NN * 3;
    const float qx = new_xyz[((size_t)b*MM + m)*3 + 0];
    const float qy = new_xyz[((size_t)b*MM + m)*3 + 1];
    const float qz = new_xyz[((size_t)b*MM + m)*3 + 2];
    const unsigned long long below = (1ull << lane) - 1ull;

    int nfound = 0, idx0 = 0;
    bool need_full = (use_grid == 0) || (use_grid && ovf[0] != 0);

    if (!need_full) {
        // clear this wave's bitmap
        uint4 z4 = make_uint4(0u, 0u, 0u, 0u);
        *(uint4*)&s_bm[wid][lane*8]     = z4;
        *(uint4*)&s_bm[wid][lane*8 + 4] = z4;

        int x0 = max(0, (int)floorf((qx - 0.1f)*10.0f - 1e-3f));
        int x1 = min(GD-1, (int)floorf((qx + 0.1f)*10.0f + 1e-3f));
        int y0 = max(0, (int)floorf((qy - 0.1f)*10.0f - 1e-3f));
        int y1 = min(GD-1, (int)floorf((qy + 0.1f)*10.0f + 1e-3f));
        int z0 = max(0, (int)floorf((qz - 0.1f)*10.0f - 1e-3f));
        int z1 = min(GD-1, (int)floorf((qz + 0.1f)*10.0f + 1e-3f));

        // ---- assign cells to lanes; prune unreachable; one parallel cnt load ----
        int myCell = -1, ncells = 0;
        int myCx = 0, myCy = 0, myCz = 0;
        for (int cx = x0; cx <= x1; ++cx)
        for (int cy = y0; cy <= y1; ++cy)
        for (int cz = z0; cz <= z1; ++cz) {
            if (lane == ncells) {
                myCell = b*CPB + (cx*GD + cy)*GD + cz;
                myCx = cx; myCy = cy; myCz = cz;
            }
            ++ncells;
        }
        int myCnt = 0, myBase = 0;
        if (myCell >= 0) {
            float xlo = myCx*0.1f, ylo = myCy*0.1f, zlo = myCz*0.1f;
            float ddx = fmaxf(fmaxf(xlo - qx, qx - (xlo + 0.1f)), 0.0f);
            float ddy = fmaxf(fmaxf(ylo - qy, qy - (ylo + 0.1f)), 0.0f);
            float ddz = fmaxf(fmaxf(zlo - qz, qz - (zlo + 0.1f)), 0.0f);
            if (ddx*ddx + ddy*ddy + ddz*ddz < R2) {
                myCnt = min(cnt[myCell], CAP);
                myBase = myCell*CAP;
            }
        }

        __builtin_amdgcn_wave_barrier();

        // ---- per-cell point tests, depth-2 software pipeline (gated loads) ----
        int cc0 = __builtin_amdgcn_readlane(myCnt, 0);
        int cb0 = __builtin_amdgcn_readlane(myBase, 0);
        float4 p0 = make_float4(0.f, 0.f, 0.f, 0.f);
        if (lane < cc0) p0 = buckets[cb0 + lane];
        for (int c = 0; c < ncells; ++c) {
            int cc1 = 0, cb1 = 0;
            if (c + 1 < ncells) {
                cc1 = __builtin_amdgcn_readlane(myCnt, c + 1);
                cb1 = __builtin_amdgcn_readlane(myBase, c + 1);
            }
            float4 pn = make_float4(0.f, 0.f, 0.f, 0.f);
            if (lane < cc1) pn = buckets[cb1 + lane];
            if (lane < cc0) {
                float dx = p0.x - qx, dy = p0.y - qy, dz = p0.z - qz;
                float d2 = dx*dx + dy*dy + dz*dz;
                if (d2 < R2) {
                    int id = __float_as_int(p0.w);
                    atomicOr(&s_bm[wid][id >> 5], 1u << (id & 31));
                }
            }
            cc0 = cc1; cb0 = cb1; p0 = pn;
        }

        __builtin_amdgcn_wave_barrier();

        // ---- bitmap -> first K indices (ascending) ----
        uint4 d0 = *(uint4*)&s_bm[wid][lane*8];
        uint4 d1 = *(uint4*)&s_bm[wid][lane*8 + 4];
        unsigned dw[8] = {d0.x, d0.y, d0.z, d0.w, d1.x, d1.y, d1.z, d1.w};
        int pc = 0;
        #pragma unroll
        for (int j = 0; j < 8; ++j) pc += __popc(dw[j]);
        int pre = pc;
        #pragma unroll
        for (int d = 1; d < 64; d <<= 1) {
            int t = __shfl_up(pre, d);
            if (lane >= d) pre += t;
        }
        int total = __shfl(pre, 63);
        int rank = pre - pc;
        nfound = min(total, KK);

        if (rank < KK) {
            #pragma unroll
            for (int j = 0; j < 8; ++j) {
                unsigned bits = dw[j];
                while (bits && rank < KK) {
                    int bpos = __builtin_ctz(bits);
                    s_idx[wid][rank] = ((lane*8 + j) << 5) + bpos;
                    bits &= bits - 1;
                    ++rank;
                }
            }
        }

        __builtin_amdgcn_wave_barrier();
        idx0 = (nfound > 0) ? s_idx[wid][0] : 0;
        __builtin_amdgcn_wave_barrier();
        if (lane >= nfound && lane < KK) s_idx[wid][lane] = idx0;
        __builtin_amdgcn_wave_barrier();
    }

    if (need_full) {
        int cntf = 0;
        for (int basep = 0; basep < NN; basep += 256) {
            float d2a[4];
            #pragma unroll
            for (int j = 0; j < 4; ++j) {
                int i = basep + (j << 6) + lane;
                float px = xb[i*3+0], py = xb[i*3+1], pz = xb[i*3+2];
                float dx = px - qx, dy = py - qy, dz = pz - qz;
                d2a[j] = dx*dx + dy*dy + dz*dz;
            }
            #pragma unroll
            for (int j = 0; j < 4; ++j) {
                bool hit = d2a[j] < R2;
                unsigned long long msk = __ballot(hit);
                if (hit) {
                    int pos = cntf + __popcll(msk & below);
                    if (pos < KK) s_idx[wid][pos] = basep + (j << 6) + lane;
                }
                cntf += __popcll(msk);
            }
            if (cntf >= KK) break;
        }
        nfound = cntf < KK ? cntf : KK;
        __builtin_amdgcn_wave_barrier();
        if (lane < KK) {
            int v = 0;
            if (nfound > 0) v = (lane < nfound) ? s_idx[wid][lane] : s_idx[wid][0];
            s_idx[wid][lane] = v;
        }
        __builtin_amdgcn_wave_barrier();
        idx0 = s_idx[wid][0];
    }

    // ---------- rel coords + normalized weights (k = lane&31) ----------
    {
        const int k = lane & 31;
        const int h = lane >> 5;
        const int ik = s_idx[wid][k];
        float px = xb[ik*3+0], py = xb[ik*3+1], pz = xb[ik*3+2];
        float rx = px - qx, ry = py - qy, rz = pz - qz;
        float dist = sqrtf(rx*rx + ry*ry + rz*rz);
        float recip = 1.0f / (dist + EPSV);
        float mult = (float)(1 + KK - nfound);
        float w = recip / ((ik == idx0) ? mult : 1.0f);
        float S = w;
        #pragma unroll
        for (int d = 1; d < 32; d <<= 1) S += __shfl_xor(S, d);
        float wk = (nfound > 0) ? (w / S) : 0.0f;
        if (h == 0) s_rel[wid][k] = make_float4(rx, ry, rz, wk);
    }
    __builtin_amdgcn_wave_barrier();

    // ---------- MLP layer 0 via MFMA: D1[o][k] = W0·G + b0 ----------
    const int l15 = lane & 15;
    const int quad = lane >> 4;

    short8 A1, A1b, Bf[4];
    if (use_grid) {
        A1  = wsA[lane];
        A1b = wsA[64 + lane];
        #pragma unroll
        for (int u = 0; u < 4; ++u) Bf[u] = wsB[lane*4 + u];
    } else {
        short8 z = {0,0,0,0,0,0,0,0};
        A1 = z; A1b = z;
        if (quad < 2) {
            #pragma unroll
            for (int j = 0; j < 8; ++j) {
                A1[j]  = f2bf(w0[l15*CCH + quad*8 + j]);
                A1b[j] = f2bf(w0[(16 + l15)*CCH + quad*8 + j]);
            }
        }
        #pragma unroll
        for (int u = 0; u < 4; ++u) {
            const float* wr = w1 + ((u << 4) + l15)*32 + (quad << 3);
            #pragma unroll
            for (int j = 0; j < 8; ++j) Bf[u][j] = f2bf(wr[j]);
        }
    }

    // B1 fragments: gathered features, lane(n=l15 -> neighbor, quad -> c=8q+j), K-pad 0
    short8 G0 = {0,0,0,0,0,0,0,0}, G1 = {0,0,0,0,0,0,0,0};
    {
        const float* fb = feat + (size_t)b * CCH * NN;
        if (quad < 2) {
            int ika = s_idx[wid][l15];
            int ikb = s_idx[wid][16 + l15];
            int cb0 = quad << 3;
            #pragma unroll
            for (int j = 0; j < 8; ++j) {
                G0[j] = f2bf(fb[(cb0 + j)*NN + ika]);
                G1[j] = f2bf(fb[(cb0 + j)*NN + ikb]);
            }
        }
    }

    v4f C0, C1;
    #pragma unroll
    for (int r = 0; r < 4; ++r) {
        C0[r] = b0[(quad << 2) + r];
        C1[r] = b0[16 + (quad << 2) + r];
    }

    v4f H00 = __builtin_amdgcn_mfma_f32_16x16x32_bf16(A1,  G0, C0, 0, 0, 0);
    v4f H01 = __builtin_amdgcn_mfma_f32_16x16x32_bf16(A1b, G0, C1, 0, 0, 0);
    v4f H10 = __builtin_amdgcn_mfma_f32_16x16x32_bf16(A1,  G1, C0, 0, 0, 0);
    v4f H11 = __builtin_amdgcn_mfma_f32_16x16x32_bf16(A1b, G1, C1, 0, 0, 0);

    // relu + pack + transpose via LDS (row = k, col = o, bf16)
    short* hb = &s_h0t[wid][0];
    {
        uint2 w;
        w.x = pk2(fmaxf(H00[0],0.f), fmaxf(H00[1],0.f));
        w.y = pk2(fmaxf(H00[2],0.f), fmaxf(H00[3],0.f));
        *(uint2*)&hb[l15*32 + (quad << 2)] = w;                // k=l15,   o=4q..4q+3
        w.x = pk2(fmaxf(H01[0],0.f), fmaxf(H01[1],0.f));
        w.y = pk2(fmaxf(H01[2],0.f), fmaxf(H01[3],0.f));
        *(uint2*)&hb[l15*32 + 16 + (quad << 2)] = w;           // o=16+4q..
        w.x = pk2(fmaxf(H10[0],0.f), fmaxf(H10[1],0.f));
        w.y = pk2(fmaxf(H10[2],0.f), fmaxf(H10[3],0.f));
        *(uint2*)&hb[(16 + l15)*32 + (quad << 2)] = w;         // k=16+l15
        w.x = pk2(fmaxf(H11[0],0.f), fmaxf(H11[1],0.f));
        w.y = pk2(fmaxf(H11[2],0.f), fmaxf(H11[3],0.f));
        *(uint2*)&hb[(16 + l15)*32 + 16 + (quad << 2)] = w;
    }
    __builtin_amdgcn_wave_barrier();

    // A-fragments for layer 1: A2[m=k][ko=o=8q+j]
    short8 A2_0 = *(short8*)&hb[l15*32 + (quad << 3)];
    short8 A2_1 = *(short8*)&hb[(16 + l15)*32 + (quad << 3)];

    // wk for this lane's 8 rows: k = 16t + 4*quad + r
    float wkv[2][4];
    #pragma unroll
    for (int t = 0; t < 2; ++t)
        #pragma unroll
        for (int r = 0; r < 4; ++r)
            wkv[t][r] = s_rel[wid][16*t + (quad << 2) + r].w;

    float* out2 = out + (size_t)BB*MM*3 + (size_t)b*96*MM;

    // ---------- layer 1 + weighted sum-pool (b1 folded into C) ----------
    float Su[4];
    #pragma unroll
    for (int u = 0; u < 4; ++u) {
        float b1u = b1[(u << 4) + l15];
        v4f Cb = {b1u, b1u, b1u, b1u};
        v4f D0 = __builtin_amdgcn_mfma_f32_16x16x32_bf16(A2_0, Bf[u], Cb, 0, 0, 0);
        v4f D1 = __builtin_amdgcn_mfma_f32_16x16x32_bf16(A2_1, Bf[u], Cb, 0, 0, 0);
        float s = 0.f;
        #pragma unroll
        for (int r = 0; r < 4; ++r)
            s += wkv[0][r]*fmaxf(D0[r], 0.f) + wkv[1][r]*fmaxf(D1[r], 0.f);
        s += __shfl_xor(s, 16);
        s += __shfl_xor(s, 32);
        Su[u] = s;
    }
    float sout = (quad == 0) ? Su[0] : (quad == 1) ? Su[1] : (quad == 2) ? Su[2] : Su[3];
    out2[(32 + lane)*MM + m] = sout;   // O = 16*quad + l15 = lane

    // ---------- xyz branch: lane = channel c, halves split k, max-pool ----------
    {
        const int c = lane & 31;
        const int h = lane >> 5;
        const float wx0 = wxyz[c*3+0], wx1 = wxyz[c*3+1], wx2 = wxyz[c*3+2];
        const float bc = bxyz[c];
        float v = 0.0f;
        #pragma unroll
        for (int kk = 0; kk < 16; ++kk) {
            float4 hr = s_rel[wid][(h << 4) + kk];
            float t = bc + wx0*hr.x + wx1*hr.y + wx2*hr.z;
            v = fmaxf(v, fmaxf(t, 0.0f));
        }
        v = fmaxf(v, __shfl_xor(v, 32));
        if (h == 0) out2[c*MM + m] = v;
    }

    if (lane == 0) {
        float* o0 = out + ((size_t)b*MM + m)*3;
        o0[0] = qx; o0[1] = qy; o0[2] = qz;
    }
}

extern "C" void kernel_launch(void* const* d_in, const int* in_sizes, int n_in,
                              void* d_out, int out_size, void* d_ws, size_t ws_size,
                              hipStream_t stream) {
    const float* xyz     = (const float*)d_in[0];
    const float* new_xyz = (const float*)d_in[1];
    const float* feat    = (const float*)d_in[2];
    const float* w0      = (const float*)d_in[3];
    const float* b0      = (const float*)d_in[4];
    const float* w1      = (const float*)d_in[5];
    const float* b1      = (const float*)d_in[6];
    const float* wxyz    = (const float*)d_in[7];
    const float* bxyz    = (const float*)d_in[8];
    float* out = (float*)d_out;

    int* ovf = (int*)d_ws;
    int* cnt = (int*)((char*)d_ws + 64);
    short8* wsA = (short8*)((char*)d_ws + WSA_OFF);
    short8* wsB = (short8*)((char*)d_ws + WSB_OFF);
    float4* buckets = (float4*)((char*)d_ws + BUCKET_OFF);
    const int use_grid = (d_ws != nullptr && ws_size >= WS_GRID) ? 1 : 0;

    if (use_grid) {
        hipMemsetAsync(d_ws, 0, BUCKET_OFF, stream);
        hipLaunchKernelGGL(k_scatter, dim3((BB*NN+255)/256), dim3(256), 0, stream,
                           xyz, w0, w1, cnt, ovf, buckets, wsA, wsB);
    }
    hipLaunchKernelGGL(grouper_fused, dim3((BB*MM)/4), dim3(256), 0, stream,
                       xyz, new_xyz, feat, w0, b0, w1, b1, wxyz, bxyz,
                       cnt, ovf, buckets, wsA, wsB, use_grid, out);
}

// Round 11
// 108.551 us; speedup vs baseline: 1.5631x; 1.0676x over previous
//
#include <hip/hip_runtime.h>
#include <math.h>
#include <limits.h>

#define BB 2
#define NN 16384
#define MM 4096
#define CCH 16
#define KK 32
#define R2 0.01f
#define EPSV 1e-8f
#define GD 10
#define CPB (GD*GD*GD)
#define CAP 56
#define NCELL (BB*CPB)                  // 2000
#define WSA_OFF 8192                    // w0 A-frags: 128 short8 = 2KB
#define WSB_OFF 10240                   // w1 B-frags: 256 short8 = 4KB
#define BUCKET_OFF 16384
#define WS_GRID (BUCKET_OFF + (size_t)NCELL*CAP*16)     // ~1.81 MB
#define NDW 512                          // bitmap dwords per wave (16384 bits)
#define TBL 768                          // candidate slot table (mean ~443, >15 sigma)
#define HST 40                           // h0t row stride in shorts (80B: 16B-aligned, 20 banks)

typedef __attribute__((ext_vector_type(8))) short short8;
typedef __attribute__((ext_vector_type(4))) float v4f;

__device__ __forceinline__ short f2bf(float f) {       // RNE float->bf16
    unsigned u = __float_as_uint(f);
    unsigned r = u + 0x7FFFu + ((u >> 16) & 1u);
    return (short)(r >> 16);
}
__device__ __forceinline__ unsigned pk2(float a, float b) {  // pack 2 bf16
    return (unsigned)(unsigned short)f2bf(a) | ((unsigned)(unsigned short)f2bf(b) << 16);
}

__device__ __forceinline__ int cell_of(float x, float y, float z) {
    int cx = min(GD-1, max(0, (int)(x * 10.0f)));
    int cy = min(GD-1, max(0, (int)(y * 10.0f)));
    int cz = min(GD-1, max(0, (int)(z * 10.0f)));
    return (cx*GD + cy)*GD + cz;
}

// ws: [0]=ovf, [64..8064)=cnt[2000], [8192)=wsA, [10240)=wsB, [16384..)=buckets
__global__ void k_scatter(const float* __restrict__ xyz,
                          const float* __restrict__ w0, const float* __restrict__ w1,
                          int* __restrict__ cnt, int* __restrict__ ovf,
                          float4* __restrict__ buckets,
                          short8* __restrict__ wsA, short8* __restrict__ wsB) {
    if (blockIdx.x == 0) {
        int t = threadIdx.x;
        if (t < 128) {   // w0 A-fragments (rows [0,16) and [16,32)), zero-padded K
            int fi = t >> 6, l = t & 63, l15 = l & 15, qd = (l >> 4) & 3;
            short8 a = {0,0,0,0,0,0,0,0};
            if (qd < 2)
                #pragma unroll
                for (int j = 0; j < 8; ++j)
                    a[j] = f2bf(w0[(fi*16 + l15)*CCH + qd*8 + j]);
            wsA[fi*64 + l] = a;
        }
        if (t < 64) {    // w1 B-fragments
            int l15 = t & 15, qd = t >> 4;
            #pragma unroll
            for (int u = 0; u < 4; ++u) {
                const float* wr = w1 + ((u << 4) + l15)*32 + (qd << 3);
                short8 bb;
                #pragma unroll
                for (int j = 0; j < 8; ++j) bb[j] = f2bf(wr[j]);
                wsB[t*4 + u] = bb;
            }
        }
    }
    int i = blockIdx.x*256 + threadIdx.x;
    if (i >= BB*NN) return;
    const float* p = xyz + (size_t)i*3;
    int b = i >> 14;
    int n = i & (NN-1);
    float x = p[0], y = p[1], z = p[2];
    int cell = b*CPB + cell_of(x, y, z);
    int slot = atomicAdd(&cnt[cell], 1);
    if (slot < CAP)
        buckets[(size_t)cell*CAP + slot] = make_float4(x, y, z, __int_as_float(n));
    else
        *ovf = 1;
}

__global__ __launch_bounds__(256, 4) void grouper_fused(
    const float* __restrict__ xyz, const float* __restrict__ new_xyz,
    const float* __restrict__ feat,
    const float* __restrict__ w0, const float* __restrict__ b0,
    const float* __restrict__ w1, const float* __restrict__ b1,
    const float* __restrict__ wxyz, const float* __restrict__ bxyz,
    const int* __restrict__ cnt, const int* __restrict__ ovf,
    const float4* __restrict__ buckets,
    const short8* __restrict__ wsA, const short8* __restrict__ wsB,
    int use_grid,
    float* __restrict__ out)
{
    const int lane = threadIdx.x & 63;
    const int wid  = threadIdx.x >> 6;
    const int q    = (blockIdx.x << 2) + wid;
    const int b    = q >> 12;
    const int m    = q & (MM - 1);

    __shared__ int s_idx[4][KK];
    __shared__ float4 s_rel[4][KK];                      // xyz = rel, w = wk
    __shared__ __align__(16) unsigned s_bm[4][NDW];      // 2KB bitmap per wave
    __shared__ __align__(16) int s_tbl[4][TBL];          // candidate slots; reused as h0t

    const float* xb = xyz + (size_t)b * NN * 3;
    const float qx = new_xyz[((size_t)b*MM + m)*3 + 0];
    const float qy = new_xyz[((size_t)b*MM + m)*3 + 1];
    const float qz = new_xyz[((size_t)b*MM + m)*3 + 2];
    const unsigned long long below = (1ull << lane) - 1ull;

    int nfound = 0, idx0 = 0;
    bool need_full = (use_grid == 0) || (use_grid && ovf[0] != 0);

    if (!need_full) {
        // clear this wave's bitmap
        uint4 z4 = make_uint4(0u, 0u, 0u, 0u);
        *(uint4*)&s_bm[wid][lane*8]     = z4;
        *(uint4*)&s_bm[wid][lane*8 + 4] = z4;

        int x0 = max(0, (int)floorf((qx - 0.1f)*10.0f - 1e-3f));
        int x1 = min(GD-1, (int)floorf((qx + 0.1f)*10.0f + 1e-3f));
        int y0 = max(0, (int)floorf((qy - 0.1f)*10.0f - 1e-3f));
        int y1 = min(GD-1, (int)floorf((qy + 0.1f)*10.0f + 1e-3f));
        int z0 = max(0, (int)floorf((qz - 0.1f)*10.0f - 1e-3f));
        int z1 = min(GD-1, (int)floorf((qz + 0.1f)*10.0f + 1e-3f));

        // ---- lane -> cell (arithmetic decomposition); AABB prune; cnt load ----
        const int nzc = z1 - z0 + 1, nyc = y1 - y0 + 1, nxc = x1 - x0 + 1;
        const int nyz = nyc * nzc;
        const int ncells = nxc * nyz;
        int myCnt = 0, myBase = 0;
        if (lane < ncells) {
            const float rnyz = 1.0f / (float)nyz;
            const float rnz  = 1.0f / (float)nzc;
            int cxr = (int)((float)lane * rnyz + 1e-4f);
            int rem = lane - cxr * nyz;
            int cyr = (int)((float)rem * rnz + 1e-4f);
            int czr = rem - cyr * nzc;
            int cx = x0 + cxr, cy = y0 + cyr, cz = z0 + czr;
            float xlo = cx*0.1f, ylo = cy*0.1f, zlo = cz*0.1f;
            float ddx = fmaxf(fmaxf(xlo - qx, qx - (xlo + 0.1f)), 0.0f);
            float ddy = fmaxf(fmaxf(ylo - qy, qy - (ylo + 0.1f)), 0.0f);
            float ddz = fmaxf(fmaxf(zlo - qz, qz - (zlo + 0.1f)), 0.0f);
            if (ddx*ddx + ddy*ddy + ddz*ddz < R2) {
                int cell = b*CPB + (cx*GD + cy)*GD + cz;
                myCnt = min(cnt[cell], CAP);
                myBase = cell*CAP;
            }
        }

        // ---- exclusive prefix of counts; total candidates ----
        int incl = myCnt;
        #pragma unroll
        for (int d = 1; d < 64; d <<= 1) {
            int t = __shfl_up(incl, d);
            if (lane >= d) incl += t;
        }
        const int total = __shfl(incl, 63);
        const int wbase = incl - myCnt;

        if (total > TBL) {
            need_full = true;          // statistically impossible; exact fallback
        } else {
            // ---- build candidate slot table (divergent, <=CAP iters) ----
            int* tbl = &s_tbl[wid][0];
            for (int t = 0; t < myCnt; ++t) tbl[wbase + t] = myBase + t;
            __builtin_amdgcn_wave_barrier();

            // ---- flattened test loop, all lanes active, depth-2 pipeline ----
            const int iters = (total + 63) >> 6;
            int j = lane;
            bool v0 = (j < total);
            int sl0 = v0 ? tbl[j] : 0;
            float4 p0 = make_float4(0.f, 0.f, 0.f, 0.f);
            if (v0) p0 = buckets[sl0];
            for (int it = 0; it < iters; ++it) {
                int jn = j + 64;
                bool v1 = (jn < total);
                int sl1 = v1 ? tbl[jn] : 0;
                float4 pn = make_float4(0.f, 0.f, 0.f, 0.f);
                if (v1) pn = buckets[sl1];
                if (v0) {
                    float dx = p0.x - qx, dy = p0.y - qy, dz = p0.z - qz;
                    if (dx*dx + dy*dy + dz*dz < R2) {
                        int id = __float_as_int(p0.w);
                        atomicOr(&s_bm[wid][id >> 5], 1u << (id & 31));
                    }
                }
                j = jn; v0 = v1; sl0 = sl1; p0 = pn;
            }

            __builtin_amdgcn_wave_barrier();

            // ---- bitmap -> first K indices (ascending) ----
            uint4 d0 = *(uint4*)&s_bm[wid][lane*8];
            uint4 d1 = *(uint4*)&s_bm[wid][lane*8 + 4];
            unsigned dw[8] = {d0.x, d0.y, d0.z, d0.w, d1.x, d1.y, d1.z, d1.w};
            int pc = 0;
            #pragma unroll
            for (int jj = 0; jj < 8; ++jj) pc += __popc(dw[jj]);
            int pre = pc;
            #pragma unroll
            for (int d = 1; d < 64; d <<= 1) {
                int t = __shfl_up(pre, d);
                if (lane >= d) pre += t;
            }
            int tt = __shfl(pre, 63);
            int rank = pre - pc;
            nfound = min(tt, KK);

            if (rank < KK) {
                #pragma unroll
                for (int jj = 0; jj < 8; ++jj) {
                    unsigned bits = dw[jj];
                    while (bits && rank < KK) {
                        int bpos = __builtin_ctz(bits);
                        s_idx[wid][rank] = ((lane*8 + jj) << 5) + bpos;
                        bits &= bits - 1;
                        ++rank;
                    }
                }
            }

            __builtin_amdgcn_wave_barrier();
            idx0 = (nfound > 0) ? s_idx[wid][0] : 0;
            __builtin_amdgcn_wave_barrier();
            if (lane >= nfound && lane < KK) s_idx[wid][lane] = idx0;
            __builtin_amdgcn_wave_barrier();
        }
    }

    if (need_full) {
        int cntf = 0;
        for (int basep = 0; basep < NN; basep += 256) {
            float d2a[4];
            #pragma unroll
            for (int j = 0; j < 4; ++j) {
                int i = basep + (j << 6) + lane;
                float px = xb[i*3+0], py = xb[i*3+1], pz = xb[i*3+2];
                float dx = px - qx, dy = py - qy, dz = pz - qz;
                d2a[j] = dx*dx + dy*dy + dz*dz;
            }
            #pragma unroll
            for (int j = 0; j < 4; ++j) {
                bool hit = d2a[j] < R2;
                unsigned long long msk = __ballot(hit);
                if (hit) {
                    int pos = cntf + __popcll(msk & below);
                    if (pos < KK) s_idx[wid][pos] = basep + (j << 6) + lane;
                }
                cntf += __popcll(msk);
            }
            if (cntf >= KK) break;
        }
        nfound = cntf < KK ? cntf : KK;
        __builtin_amdgcn_wave_barrier();
        if (lane < KK) {
            int v = 0;
            if (nfound > 0) v = (lane < nfound) ? s_idx[wid][lane] : s_idx[wid][0];
            s_idx[wid][lane] = v;
        }
        __builtin_amdgcn_wave_barrier();
        idx0 = s_idx[wid][0];
    }

    // ---------- rel coords + normalized weights (k = lane&31) ----------
    {
        const int k = lane & 31;
        const int h = lane >> 5;
        const int ik = s_idx[wid][k];
        float px = xb[ik*3+0], py = xb[ik*3+1], pz = xb[ik*3+2];
        float rx = px - qx, ry = py - qy, rz = pz - qz;
        float dist = sqrtf(rx*rx + ry*ry + rz*rz);
        float recip = 1.0f / (dist + EPSV);
        float mult = (float)(1 + KK - nfound);
        float w = recip / ((ik == idx0) ? mult : 1.0f);
        float S = w;
        #pragma unroll
        for (int d = 1; d < 32; d <<= 1) S += __shfl_xor(S, d);
        float wk = (nfound > 0) ? (w / S) : 0.0f;
        if (h == 0) s_rel[wid][k] = make_float4(rx, ry, rz, wk);
    }
    __builtin_amdgcn_wave_barrier();

    // ---------- MLP layer 0 via MFMA: D1[o][k] = W0·G + b0 ----------
    const int l15 = lane & 15;
    const int quad = lane >> 4;

    short8 A1, A1b, Bf[4];
    if (use_grid) {
        A1  = wsA[lane];
        A1b = wsA[64 + lane];
        #pragma unroll
        for (int u = 0; u < 4; ++u) Bf[u] = wsB[lane*4 + u];
    } else {
        short8 z = {0,0,0,0,0,0,0,0};
        A1 = z; A1b = z;
        if (quad < 2) {
            #pragma unroll
            for (int j = 0; j < 8; ++j) {
                A1[j]  = f2bf(w0[l15*CCH + quad*8 + j]);
                A1b[j] = f2bf(w0[(16 + l15)*CCH + quad*8 + j]);
            }
        }
        #pragma unroll
        for (int u = 0; u < 4; ++u) {
            const float* wr = w1 + ((u << 4) + l15)*32 + (quad << 3);
            #pragma unroll
            for (int j = 0; j < 8; ++j) Bf[u][j] = f2bf(wr[j]);
        }
    }

    // B1 fragments: gathered features, lane(n=l15 -> neighbor, quad -> c=8q+j), K-pad 0
    short8 G0 = {0,0,0,0,0,0,0,0}, G1 = {0,0,0,0,0,0,0,0};
    {
        const float* fb = feat + (size_t)b * CCH * NN;
        if (quad < 2) {
            int ika = s_idx[wid][l15];
            int ikb = s_idx[wid][16 + l15];
            int cb0 = quad << 3;
            #pragma unroll
            for (int j = 0; j < 8; ++j) {
                G0[j] = f2bf(fb[(cb0 + j)*NN + ika]);
                G1[j] = f2bf(fb[(cb0 + j)*NN + ikb]);
            }
        }
    }

    v4f C0, C1;
    #pragma unroll
    for (int r = 0; r < 4; ++r) {
        C0[r] = b0[(quad << 2) + r];
        C1[r] = b0[16 + (quad << 2) + r];
    }

    v4f H00 = __builtin_amdgcn_mfma_f32_16x16x32_bf16(A1,  G0, C0, 0, 0, 0);
    v4f H01 = __builtin_amdgcn_mfma_f32_16x16x32_bf16(A1b, G0, C1, 0, 0, 0);
    v4f H10 = __builtin_amdgcn_mfma_f32_16x16x32_bf16(A1,  G1, C0, 0, 0, 0);
    v4f H11 = __builtin_amdgcn_mfma_f32_16x16x32_bf16(A1b, G1, C1, 0, 0, 0);

    // relu + pack + transpose via LDS (row = k, col = o, bf16; stride HST=40: no conflicts)
    __builtin_amdgcn_wave_barrier();               // table phase fully done
    short* hb = (short*)&s_tbl[wid][0];
    {
        uint2 w;
        w.x = pk2(fmaxf(H00[0],0.f), fmaxf(H00[1],0.f));
        w.y = pk2(fmaxf(H00[2],0.f), fmaxf(H00[3],0.f));
        *(uint2*)&hb[l15*HST + (quad << 2)] = w;               // k=l15,   o=4q..4q+3
        w.x = pk2(fmaxf(H01[0],0.f), fmaxf(H01[1],0.f));
        w.y = pk2(fmaxf(H01[2],0.f), fmaxf(H01[3],0.f));
        *(uint2*)&hb[l15*HST + 16 + (quad << 2)] = w;          // o=16+4q..
        w.x = pk2(fmaxf(H10[0],0.f), fmaxf(H10[1],0.f));
        w.y = pk2(fmaxf(H10[2],0.f), fmaxf(H10[3],0.f));
        *(uint2*)&hb[(16 + l15)*HST + (quad << 2)] = w;        // k=16+l15
        w.x = pk2(fmaxf(H11[0],0.f), fmaxf(H11[1],0.f));
        w.y = pk2(fmaxf(H11[2],0.f), fmaxf(H11[3],0.f));
        *(uint2*)&hb[(16 + l15)*HST + 16 + (quad << 2)] = w;
    }
    __builtin_amdgcn_wave_barrier();

    // A-fragments for layer 1: A2[m=k][ko=o=8q+j]
    short8 A2_0 = *(short8*)&hb[l15*HST + (quad << 3)];
    short8 A2_1 = *(short8*)&hb[(16 + l15)*HST + (quad << 3)];

    // wk for this lane's 8 rows: k = 16t + 4*quad + r
    float wkv[2][4];
    #pragma unroll
    for (int t = 0; t < 2; ++t)
        #pragma unroll
        for (int r = 0; r < 4; ++r)
            wkv[t][r] = s_rel[wid][16*t + (quad << 2) + r].w;

    float* out2 = out + (size_t)BB*MM*3 + (size_t)b*96*MM;

    // ---------- layer 1 + weighted sum-pool (b1 folded into C) ----------
    float Su[4];
    #pragma unroll
    for (int u = 0; u < 4; ++u) {
        float b1u = b1[(u << 4) + l15];
        v4f Cb = {b1u, b1u, b1u, b1u};
        v4f D0 = __builtin_amdgcn_mfma_f32_16x16x32_bf16(A2_0, Bf[u], Cb, 0, 0, 0);
        v4f D1 = __builtin_amdgcn_mfma_f32_16x16x32_bf16(A2_1, Bf[u], Cb, 0, 0, 0);
        float s = 0.f;
        #pragma unroll
        for (int r = 0; r < 4; ++r)
            s += wkv[0][r]*fmaxf(D0[r], 0.f) + wkv[1][r]*fmaxf(D1[r], 0.f);
        s += __shfl_xor(s, 16);
        s += __shfl_xor(s, 32);
        Su[u] = s;
    }
    float sout = (quad == 0) ? Su[0] : (quad == 1) ? Su[1] : (quad == 2) ? Su[2] : Su[3];
    out2[(32 + lane)*MM + m] = sout;   // O = 16*quad + l15 = lane

    // ---------- xyz branch: lane = channel c, halves split k, max-pool ----------
    {
        const int c = lane & 31;
        const int h = lane >> 5;
        const float wx0 = wxyz[c*3+0], wx1 = wxyz[c*3+1], wx2 = wxyz[c*3+2];
        const float bc = bxyz[c];
        float v = 0.0f;
        #pragma unroll
        for (int kk = 0; kk < 16; ++kk) {
            float4 hr = s_rel[wid][(h << 4) + kk];
            float t = bc + wx0*hr.x + wx1*hr.y + wx2*hr.z;
            v = fmaxf(v, fmaxf(t, 0.0f));
        }
        v = fmaxf(v, __shfl_xor(v, 32));
        if (h == 0) out2[c*MM + m] = v;
    }

    if (lane == 0) {
        float* o0 = out + ((size_t)b*MM + m)*3;
        o0[0] = qx; o0[1] = qy; o0[2] = qz;
    }
}

extern "C" void kernel_launch(void* const* d_in, const int* in_sizes, int n_in,
                              void* d_out, int out_size, void* d_ws, size_t ws_size,
                              hipStream_t stream) {
    const float* xyz     = (const float*)d_in[0];
    const float* new_xyz = (const float*)d_in[1];
    const float* feat    = (const float*)d_in[2];
    const float* w0      = (const float*)d_in[3];
    const float* b0      = (const float*)d_in[4];
    const float* w1      = (const float*)d_in[5];
    const float* b1      = (const float*)d_in[6];
    const float* wxyz    = (const float*)d_in[7];
    const float* bxyz    = (const float*)d_in[8];
    float* out = (float*)d_out;

    int* ovf = (int*)d_ws;
    int* cnt = (int*)((char*)d_ws + 64);
    short8* wsA = (short8*)((char*)d_ws + WSA_OFF);
    short8* wsB = (short8*)((char*)d_ws + WSB_OFF);
    float4* buckets = (float4*)((char*)d_ws + BUCKET_OFF);
    const int use_grid = (d_ws != nullptr && ws_size >= WS_GRID) ? 1 : 0;

    if (use_grid) {
        hipMemsetAsync(d_ws, 0, BUCKET_OFF, stream);
        hipLaunchKernelGGL(k_scatter, dim3((BB*NN+255)/256), dim3(256), 0, stream,
                           xyz, w0, w1, cnt, ovf, buckets, wsA, wsB);
    }
    hipLaunchKernelGGL(grouper_fused, dim3((BB*MM)/4), dim3(256), 0, stream,
                       xyz, new_xyz, feat, w0, b0, w1, b1, wxyz, bxyz,
                       cnt, ovf, buckets, wsA, wsB, use_grid, out);
}

// Round 12
// 96.461 us; speedup vs baseline: 1.7591x; 1.1253x over previous
//
#include <hip/hip_runtime.h>
#include <math.h>
#include <limits.h>

#define BB 2
#define NN 16384
#define MM 4096
#define CCH 16
#define KK 32
#define R2 0.01f
#define EPSV 1e-8f
#define GD 10
#define CPB (GD*GD*GD)
#define CAP 56
#define NCELL (BB*CPB)                  // 2000
#define WSA_OFF 8192                    // w0 A-frags: 128 short8 = 2KB
#define WSB_OFF 10240                   // w1 B-frags: 256 short8 = 4KB
#define BUCKET_OFF 16384
#define FEATT_OFF (2*1024*1024)         // bf16 featT: [B*N][16] = 1MB
#define WS_GRID (BUCKET_OFF + (size_t)NCELL*CAP*16)     // ~1.81 MB
#define WS_FT   (FEATT_OFF + (size_t)BB*NN*CCH*2)       // 3.05 MB
#define NDW 512                          // bitmap dwords per wave (16384 bits)
#define TBL 768                          // candidate slot table (mean ~443, >15 sigma)
#define HST 40                           // h0t row stride in shorts (80B: 16B-aligned)

typedef __attribute__((ext_vector_type(8))) short short8;
typedef __attribute__((ext_vector_type(4))) float v4f;

__device__ __forceinline__ short f2bf(float f) {       // RNE float->bf16
    unsigned u = __float_as_uint(f);
    unsigned r = u + 0x7FFFu + ((u >> 16) & 1u);
    return (short)(r >> 16);
}
__device__ __forceinline__ unsigned pk2(float a, float b) {  // pack 2 bf16
    return (unsigned)(unsigned short)f2bf(a) | ((unsigned)(unsigned short)f2bf(b) << 16);
}

__device__ __forceinline__ int cell_of(float x, float y, float z) {
    int cx = min(GD-1, max(0, (int)(x * 10.0f)));
    int cy = min(GD-1, max(0, (int)(y * 10.0f)));
    int cz = min(GD-1, max(0, (int)(z * 10.0f)));
    return (cx*GD + cy)*GD + cz;
}

// ws: [0]=ovf, [64..8064)=cnt, [8192)=wsA, [10240)=wsB, [16384..)=buckets, [2MB..)=ftb
__global__ void k_scatter(const float* __restrict__ xyz, const float* __restrict__ feat,
                          const float* __restrict__ w0, const float* __restrict__ w1,
                          int* __restrict__ cnt, int* __restrict__ ovf,
                          float4* __restrict__ buckets,
                          short8* __restrict__ wsA, short8* __restrict__ wsB,
                          uint4* __restrict__ ftb, int use_ft) {
    if (blockIdx.x == 0) {
        int t = threadIdx.x;
        if (t < 128) {   // w0 A-fragments (rows [0,16) and [16,32)), zero-padded K
            int fi = t >> 6, l = t & 63, l15 = l & 15, qd = (l >> 4) & 3;
            short8 a = {0,0,0,0,0,0,0,0};
            if (qd < 2)
                #pragma unroll
                for (int j = 0; j < 8; ++j)
                    a[j] = f2bf(w0[(fi*16 + l15)*CCH + qd*8 + j]);
            wsA[fi*64 + l] = a;
        }
        if (t < 64) {    // w1 B-fragments
            int l15 = t & 15, qd = t >> 4;
            #pragma unroll
            for (int u = 0; u < 4; ++u) {
                const float* wr = w1 + ((u << 4) + l15)*32 + (qd << 3);
                short8 bb;
                #pragma unroll
                for (int j = 0; j < 8; ++j) bb[j] = f2bf(wr[j]);
                wsB[t*4 + u] = bb;
            }
        }
    }
    int i = blockIdx.x*256 + threadIdx.x;
    if (i >= BB*NN) return;
    const float* p = xyz + (size_t)i*3;
    int b = i >> 14;
    int n = i & (NN-1);
    float x = p[0], y = p[1], z = p[2];
    int cell = b*CPB + cell_of(x, y, z);
    int slot = atomicAdd(&cnt[cell], 1);
    if (slot < CAP)
        buckets[(size_t)cell*CAP + slot] = make_float4(x, y, z, __int_as_float(n));
    else
        *ovf = 1;
    if (use_ft) {   // bf16 transposed features, MFMA B-fragment-ready (coalesced r/w)
        const float* fb = feat + (size_t)b*CCH*NN + n;
        unsigned d[8];
        #pragma unroll
        for (int c2 = 0; c2 < 8; ++c2)
            d[c2] = pk2(fb[(2*c2)*NN], fb[(2*c2+1)*NN]);
        ftb[(size_t)i*2 + 0] = make_uint4(d[0], d[1], d[2], d[3]);
        ftb[(size_t)i*2 + 1] = make_uint4(d[4], d[5], d[6], d[7]);
    }
}

__global__ __launch_bounds__(256, 4) void grouper_fused(
    const float* __restrict__ xyz, const float* __restrict__ new_xyz,
    const float* __restrict__ feat,
    const float* __restrict__ w0, const float* __restrict__ b0,
    const float* __restrict__ w1, const float* __restrict__ b1,
    const float* __restrict__ wxyz, const float* __restrict__ bxyz,
    const int* __restrict__ cnt, const int* __restrict__ ovf,
    const float4* __restrict__ buckets,
    const short8* __restrict__ wsA, const short8* __restrict__ wsB,
    const short8* __restrict__ ftb,
    int use_grid, int use_ft,
    float* __restrict__ out)
{
    const int lane = threadIdx.x & 63;
    const int wid  = threadIdx.x >> 6;
    const int q    = (blockIdx.x << 2) + wid;
    const int b    = q >> 12;
    const int m    = q & (MM - 1);

    __shared__ int s_idx[4][KK];
    __shared__ float4 s_rel[4][KK];                      // xyz = rel, w = wk
    __shared__ __align__(16) unsigned s_bm[4][NDW];      // 2KB bitmap per wave
    __shared__ __align__(16) int s_tbl[4][TBL];          // candidate slots; reused as h0t

    const float* xb = xyz + (size_t)b * NN * 3;
    const float qx = new_xyz[((size_t)b*MM + m)*3 + 0];
    const float qy = new_xyz[((size_t)b*MM + m)*3 + 1];
    const float qz = new_xyz[((size_t)b*MM + m)*3 + 2];
    const unsigned long long below = (1ull << lane) - 1ull;

    int nfound = 0, idx0 = 0;
    bool need_full = (use_grid == 0) || (use_grid && ovf[0] != 0);

    if (!need_full) {
        // clear this wave's bitmap
        uint4 z4 = make_uint4(0u, 0u, 0u, 0u);
        *(uint4*)&s_bm[wid][lane*8]     = z4;
        *(uint4*)&s_bm[wid][lane*8 + 4] = z4;

        int x0 = max(0, (int)floorf((qx - 0.1f)*10.0f - 1e-3f));
        int x1 = min(GD-1, (int)floorf((qx + 0.1f)*10.0f + 1e-3f));
        int y0 = max(0, (int)floorf((qy - 0.1f)*10.0f - 1e-3f));
        int y1 = min(GD-1, (int)floorf((qy + 0.1f)*10.0f + 1e-3f));
        int z0 = max(0, (int)floorf((qz - 0.1f)*10.0f - 1e-3f));
        int z1 = min(GD-1, (int)floorf((qz + 0.1f)*10.0f + 1e-3f));

        // ---- lane -> cell (arithmetic decomposition); AABB prune; cnt load ----
        const int nzc = z1 - z0 + 1, nyc = y1 - y0 + 1, nxc = x1 - x0 + 1;
        const int nyz = nyc * nzc;
        const int ncells = nxc * nyz;
        int myCnt = 0, myBase = 0;
        if (lane < ncells) {
            const float rnyz = 1.0f / (float)nyz;
            const float rnz  = 1.0f / (float)nzc;
            int cxr = (int)((float)lane * rnyz + 1e-4f);
            int rem = lane - cxr * nyz;
            int cyr = (int)((float)rem * rnz + 1e-4f);
            int czr = rem - cyr * nzc;
            int cx = x0 + cxr, cy = y0 + cyr, cz = z0 + czr;
            float xlo = cx*0.1f, ylo = cy*0.1f, zlo = cz*0.1f;
            float ddx = fmaxf(fmaxf(xlo - qx, qx - (xlo + 0.1f)), 0.0f);
            float ddy = fmaxf(fmaxf(ylo - qy, qy - (ylo + 0.1f)), 0.0f);
            float ddz = fmaxf(fmaxf(zlo - qz, qz - (zlo + 0.1f)), 0.0f);
            if (ddx*ddx + ddy*ddy + ddz*ddz < R2) {
                int cell = b*CPB + (cx*GD + cy)*GD + cz;
                myCnt = min(cnt[cell], CAP);
                myBase = cell*CAP;
            }
        }

        // ---- exclusive prefix of counts; total candidates ----
        int incl = myCnt;
        #pragma unroll
        for (int d = 1; d < 64; d <<= 1) {
            int t = __shfl_up(incl, d);
            if (lane >= d) incl += t;
        }
        const int total = __shfl(incl, 63);
        const int wbase = incl - myCnt;

        if (total > TBL) {
            need_full = true;          // statistically impossible; exact fallback
        } else {
            // ---- build candidate slot table (divergent, <=CAP iters) ----
            int* tbl = &s_tbl[wid][0];
            for (int t = 0; t < myCnt; ++t) tbl[wbase + t] = myBase + t;
            __builtin_amdgcn_wave_barrier();

            // ---- flattened test loop, all lanes active, depth-2 pipeline ----
            const int iters = (total + 63) >> 6;
            int j = lane;
            bool v0 = (j < total);
            int sl0 = v0 ? tbl[j] : 0;
            float4 p0 = make_float4(0.f, 0.f, 0.f, 0.f);
            if (v0) p0 = buckets[sl0];
            for (int it = 0; it < iters; ++it) {
                int jn = j + 64;
                bool v1 = (jn < total);
                int sl1 = v1 ? tbl[jn] : 0;
                float4 pn = make_float4(0.f, 0.f, 0.f, 0.f);
                if (v1) pn = buckets[sl1];
                if (v0) {
                    float dx = p0.x - qx, dy = p0.y - qy, dz = p0.z - qz;
                    if (dx*dx + dy*dy + dz*dz < R2) {
                        int id = __float_as_int(p0.w);
                        atomicOr(&s_bm[wid][id >> 5], 1u << (id & 31));
                    }
                }
                j = jn; v0 = v1; sl0 = sl1; p0 = pn;
            }

            __builtin_amdgcn_wave_barrier();

            // ---- bitmap -> first K indices (ascending) ----
            uint4 d0 = *(uint4*)&s_bm[wid][lane*8];
            uint4 d1 = *(uint4*)&s_bm[wid][lane*8 + 4];
            unsigned dw[8] = {d0.x, d0.y, d0.z, d0.w, d1.x, d1.y, d1.z, d1.w};
            int pc = 0;
            #pragma unroll
            for (int jj = 0; jj < 8; ++jj) pc += __popc(dw[jj]);
            int pre = pc;
            #pragma unroll
            for (int d = 1; d < 64; d <<= 1) {
                int t = __shfl_up(pre, d);
                if (lane >= d) pre += t;
            }
            int tt = __shfl(pre, 63);
            int rank = pre - pc;
            nfound = min(tt, KK);

            if (rank < KK) {
                #pragma unroll
                for (int jj = 0; jj < 8; ++jj) {
                    unsigned bits = dw[jj];
                    while (bits && rank < KK) {
                        int bpos = __builtin_ctz(bits);
                        s_idx[wid][rank] = ((lane*8 + jj) << 5) + bpos;
                        bits &= bits - 1;
                        ++rank;
                    }
                }
            }

            __builtin_amdgcn_wave_barrier();
            idx0 = (nfound > 0) ? s_idx[wid][0] : 0;
            __builtin_amdgcn_wave_barrier();
            if (lane >= nfound && lane < KK) s_idx[wid][lane] = idx0;
            __builtin_amdgcn_wave_barrier();
        }
    }

    if (need_full) {
        int cntf = 0;
        for (int basep = 0; basep < NN; basep += 256) {
            float d2a[4];
            #pragma unroll
            for (int j = 0; j < 4; ++j) {
                int i = basep + (j << 6) + lane;
                float px = xb[i*3+0], py = xb[i*3+1], pz = xb[i*3+2];
                float dx = px - qx, dy = py - qy, dz = pz - qz;
                d2a[j] = dx*dx + dy*dy + dz*dz;
            }
            #pragma unroll
            for (int j = 0; j < 4; ++j) {
                bool hit = d2a[j] < R2;
                unsigned long long msk = __ballot(hit);
                if (hit) {
                    int pos = cntf + __popcll(msk & below);
                    if (pos < KK) s_idx[wid][pos] = basep + (j << 6) + lane;
                }
                cntf += __popcll(msk);
            }
            if (cntf >= KK) break;
        }
        nfound = cntf < KK ? cntf : KK;
        __builtin_amdgcn_wave_barrier();
        if (lane < KK) {
            int v = 0;
            if (nfound > 0) v = (lane < nfound) ? s_idx[wid][lane] : s_idx[wid][0];
            s_idx[wid][lane] = v;
        }
        __builtin_amdgcn_wave_barrier();
        idx0 = s_idx[wid][0];
    }

    // ---------- rel coords + normalized weights (k = lane&31) ----------
    {
        const int k = lane & 31;
        const int h = lane >> 5;
        const int ik = s_idx[wid][k];
        float px = xb[ik*3+0], py = xb[ik*3+1], pz = xb[ik*3+2];
        float rx = px - qx, ry = py - qy, rz = pz - qz;
        float dist = sqrtf(rx*rx + ry*ry + rz*rz);
        float recip = 1.0f / (dist + EPSV);
        float mult = (float)(1 + KK - nfound);
        float w = recip / ((ik == idx0) ? mult : 1.0f);
        float S = w;
        #pragma unroll
        for (int d = 1; d < 32; d <<= 1) S += __shfl_xor(S, d);
        float wk = (nfound > 0) ? (w / S) : 0.0f;
        if (h == 0) s_rel[wid][k] = make_float4(rx, ry, rz, wk);
    }
    __builtin_amdgcn_wave_barrier();

    // ---------- MLP layer 0 via MFMA: D1[o][k] = W0·G + b0 ----------
    const int l15 = lane & 15;
    const int quad = lane >> 4;

    short8 A1, A1b, Bf[4];
    if (use_grid) {
        A1  = wsA[lane];
        A1b = wsA[64 + lane];
        #pragma unroll
        for (int u = 0; u < 4; ++u) Bf[u] = wsB[lane*4 + u];
    } else {
        short8 z = {0,0,0,0,0,0,0,0};
        A1 = z; A1b = z;
        if (quad < 2) {
            #pragma unroll
            for (int j = 0; j < 8; ++j) {
                A1[j]  = f2bf(w0[l15*CCH + quad*8 + j]);
                A1b[j] = f2bf(w0[(16 + l15)*CCH + quad*8 + j]);
            }
        }
        #pragma unroll
        for (int u = 0; u < 4; ++u) {
            const float* wr = w1 + ((u << 4) + l15)*32 + (quad << 3);
            #pragma unroll
            for (int j = 0; j < 8; ++j) Bf[u][j] = f2bf(wr[j]);
        }
    }

    // B1 fragments: gathered features (bf16-packed table: one 16B load per neighbor)
    short8 G0 = {0,0,0,0,0,0,0,0}, G1 = {0,0,0,0,0,0,0,0};
    if (quad < 2) {
        int ika = s_idx[wid][l15];
        int ikb = s_idx[wid][16 + l15];
        if (use_ft) {
            G0 = ftb[(size_t)(b*NN + ika)*2 + quad];
            G1 = ftb[(size_t)(b*NN + ikb)*2 + quad];
        } else {
            const float* fb = feat + (size_t)b * CCH * NN;
            int cb0 = quad << 3;
            #pragma unroll
            for (int j = 0; j < 8; ++j) {
                G0[j] = f2bf(fb[(cb0 + j)*NN + ika]);
                G1[j] = f2bf(fb[(cb0 + j)*NN + ikb]);
            }
        }
    }

    v4f C0, C1;
    #pragma unroll
    for (int r = 0; r < 4; ++r) {
        C0[r] = b0[(quad << 2) + r];
        C1[r] = b0[16 + (quad << 2) + r];
    }

    v4f H00 = __builtin_amdgcn_mfma_f32_16x16x32_bf16(A1,  G0, C0, 0, 0, 0);
    v4f H01 = __builtin_amdgcn_mfma_f32_16x16x32_bf16(A1b, G0, C1, 0, 0, 0);
    v4f H10 = __builtin_amdgcn_mfma_f32_16x16x32_bf16(A1,  G1, C0, 0, 0, 0);
    v4f H11 = __builtin_amdgcn_mfma_f32_16x16x32_bf16(A1b, G1, C1, 0, 0, 0);

    // relu + pack + transpose via LDS (row = k, col = o, bf16; stride HST=40)
    __builtin_amdgcn_wave_barrier();               // table phase fully done
    short* hb = (short*)&s_tbl[wid][0];
    {
        uint2 w;
        w.x = pk2(fmaxf(H00[0],0.f), fmaxf(H00[1],0.f));
        w.y = pk2(fmaxf(H00[2],0.f), fmaxf(H00[3],0.f));
        *(uint2*)&hb[l15*HST + (quad << 2)] = w;               // k=l15,   o=4q..4q+3
        w.x = pk2(fmaxf(H01[0],0.f), fmaxf(H01[1],0.f));
        w.y = pk2(fmaxf(H01[2],0.f), fmaxf(H01[3],0.f));
        *(uint2*)&hb[l15*HST + 16 + (quad << 2)] = w;          // o=16+4q..
        w.x = pk2(fmaxf(H10[0],0.f), fmaxf(H10[1],0.f));
        w.y = pk2(fmaxf(H10[2],0.f), fmaxf(H10[3],0.f));
        *(uint2*)&hb[(16 + l15)*HST + (quad << 2)] = w;        // k=16+l15
        w.x = pk2(fmaxf(H11[0],0.f), fmaxf(H11[1],0.f));
        w.y = pk2(fmaxf(H11[2],0.f), fmaxf(H11[3],0.f));
        *(uint2*)&hb[(16 + l15)*HST + 16 + (quad << 2)] = w;
    }
    __builtin_amdgcn_wave_barrier();

    // A-fragments for layer 1: A2[m=k][ko=o=8q+j]
    short8 A2_0 = *(short8*)&hb[l15*HST + (quad << 3)];
    short8 A2_1 = *(short8*)&hb[(16 + l15)*HST + (quad << 3)];

    // wk for this lane's 8 rows: k = 16t + 4*quad + r
    float wkv[2][4];
    #pragma unroll
    for (int t = 0; t < 2; ++t)
        #pragma unroll
        for (int r = 0; r < 4; ++r)
            wkv[t][r] = s_rel[wid][16*t + (quad << 2) + r].w;

    float* out2 = out + (size_t)BB*MM*3 + (size_t)b*96*MM;

    // ---------- layer 1 + weighted sum-pool (b1 folded into C) ----------
    float Su[4];
    #pragma unroll
    for (int u = 0; u < 4; ++u) {
        float b1u = b1[(u << 4) + l15];
        v4f Cb = {b1u, b1u, b1u, b1u};
        v4f D0 = __builtin_amdgcn_mfma_f32_16x16x32_bf16(A2_0, Bf[u], Cb, 0, 0, 0);
        v4f D1 = __builtin_amdgcn_mfma_f32_16x16x32_bf16(A2_1, Bf[u], Cb, 0, 0, 0);
        float s = 0.f;
        #pragma unroll
        for (int r = 0; r < 4; ++r)
            s += wkv[0][r]*fmaxf(D0[r], 0.f) + wkv[1][r]*fmaxf(D1[r], 0.f);
        s += __shfl_xor(s, 16);
        s += __shfl_xor(s, 32);
        Su[u] = s;
    }
    float sout = (quad == 0) ? Su[0] : (quad == 1) ? Su[1] : (quad == 2) ? Su[2] : Su[3];
    out2[(32 + lane)*MM + m] = sout;   // O = 16*quad + l15 = lane

    // ---------- xyz branch: lane = channel c, halves split k, max-pool ----------
    {
        const int c = lane & 31;
        const int h = lane >> 5;
        const float wx0 = wxyz[c*3+0], wx1 = wxyz[c*3+1], wx2 = wxyz[c*3+2];
        const float bc = bxyz[c];
        float v = 0.0f;
        #pragma unroll
        for (int kk = 0; kk < 16; ++kk) {
            float4 hr = s_rel[wid][(h << 4) + kk];
            float t = bc + wx0*hr.x + wx1*hr.y + wx2*hr.z;
            v = fmaxf(v, fmaxf(t, 0.0f));
        }
        v = fmaxf(v, __shfl_xor(v, 32));
        if (h == 0) out2[c*MM + m] = v;
    }

    if (lane == 0) {
        float* o0 = out + ((size_t)b*MM + m)*3;
        o0[0] = qx; o0[1] = qy; o0[2] = qz;
    }
}

extern "C" void kernel_launch(void* const* d_in, const int* in_sizes, int n_in,
                              void* d_out, int out_size, void* d_ws, size_t ws_size,
                              hipStream_t stream) {
    const float* xyz     = (const float*)d_in[0];
    const float* new_xyz = (const float*)d_in[1];
    const float* feat    = (const float*)d_in[2];
    const float* w0      = (const float*)d_in[3];
    const float* b0      = (const float*)d_in[4];
    const float* w1      = (const float*)d_in[5];
    const float* b1      = (const float*)d_in[6];
    const float* wxyz    = (const float*)d_in[7];
    const float* bxyz    = (const float*)d_in[8];
    float* out = (float*)d_out;

    int* ovf = (int*)d_ws;
    int* cnt = (int*)((char*)d_ws + 64);
    short8* wsA = (short8*)((char*)d_ws + WSA_OFF);
    short8* wsB = (short8*)((char*)d_ws + WSB_OFF);
    float4* buckets = (float4*)((char*)d_ws + BUCKET_OFF);
    uint4* ftb4 = (uint4*)((char*)d_ws + FEATT_OFF);
    const short8* ftb = (const short8*)((char*)d_ws + FEATT_OFF);
    const int use_grid = (d_ws != nullptr && ws_size >= WS_GRID) ? 1 : 0;
    const int use_ft   = (d_ws != nullptr && ws_size >= WS_FT) ? 1 : 0;

    if (use_grid) {
        hipMemsetAsync(d_ws, 0, BUCKET_OFF, stream);
        hipLaunchKernelGGL(k_scatter, dim3((BB*NN+255)/256), dim3(256), 0, stream,
                           xyz, feat, w0, w1, cnt, ovf, buckets, wsA, wsB, ftb4, use_ft);
    }
    hipLaunchKernelGGL(grouper_fused, dim3((BB*MM)/4), dim3(256), 0, stream,
                       xyz, new_xyz, feat, w0, b0, w1, b1, wxyz, bxyz,
                       cnt, ovf, buckets, wsA, wsB, ftb, use_grid, use_ft, out);
}